// Round 1
// baseline (2185.565 us; speedup 1.0000x reference)
//
#include <hip/hip_runtime.h>
#include <math.h>

#define NN 50000
#define EE 800000

// ------------------------------------------------------------------
// GEMM: C[M][NC] = A[M][K] @ B[K][NC] + bias[NC]   (fp32)
// BM=128, BN=64, BK=16, block 256 threads, 8x4 micro-tile
// ------------------------------------------------------------------
__global__ __launch_bounds__(256) void gemm_bias(
    const float* __restrict__ A, const float* __restrict__ B,
    const float* __restrict__ bias, float* __restrict__ C,
    int M, int K, int NC)
{
    __shared__ float As[16][128];
    __shared__ float Bs[16][64];
    const int tid = threadIdx.x;
    const int tx = tid & 15, ty = tid >> 4;
    const int rowBase = blockIdx.x * 128;
    const int colBase = blockIdx.y * 64;

    float acc[8][4];
#pragma unroll
    for (int i = 0; i < 8; ++i)
#pragma unroll
        for (int j = 0; j < 4; ++j) acc[i][j] = 0.f;

    for (int k0 = 0; k0 < K; k0 += 16) {
#pragma unroll
        for (int l = 0; l < 2; ++l) {
            int fidx = tid * 2 + l;        // 0..511
            int r = fidx >> 2;             // 0..127
            int kq = fidx & 3;             // which float4 in the 16-k strip
            float4 v = make_float4(0.f, 0.f, 0.f, 0.f);
            int grow = rowBase + r;
            if (grow < M)
                v = *(const float4*)(A + (size_t)grow * K + k0 + kq * 4);
            As[kq * 4 + 0][r] = v.x;
            As[kq * 4 + 1][r] = v.y;
            As[kq * 4 + 2][r] = v.z;
            As[kq * 4 + 3][r] = v.w;
        }
        {
            int kb = tid >> 4, cq = tid & 15;
            *(float4*)&Bs[kb][cq * 4] =
                *(const float4*)(B + (size_t)(k0 + kb) * NC + colBase + cq * 4);
        }
        __syncthreads();
#pragma unroll
        for (int k = 0; k < 16; ++k) {
            float4 a0 = *(float4*)&As[k][ty * 8];
            float4 a1 = *(float4*)&As[k][ty * 8 + 4];
            float4 b0 = *(float4*)&Bs[k][tx * 4];
            float av[8] = {a0.x, a0.y, a0.z, a0.w, a1.x, a1.y, a1.z, a1.w};
            float bv[4] = {b0.x, b0.y, b0.z, b0.w};
#pragma unroll
            for (int i = 0; i < 8; ++i)
#pragma unroll
                for (int j = 0; j < 4; ++j)
                    acc[i][j] = fmaf(av[i], bv[j], acc[i][j]);
        }
        __syncthreads();
    }

    float4 bb = *(const float4*)(bias + colBase + tx * 4);
#pragma unroll
    for (int i = 0; i < 8; ++i) {
        int grow = rowBase + ty * 8 + i;
        if (grow >= M) continue;
        float4 o = make_float4(acc[i][0] + bb.x, acc[i][1] + bb.y,
                               acc[i][2] + bb.z, acc[i][3] + bb.w);
        *(float4*)(C + (size_t)grow * NC + colBase + tx * 4) = o;
    }
}

// ------------------------------------------------------------------
// CSR build: histogram -> scan -> scatter
// ------------------------------------------------------------------
__global__ __launch_bounds__(256) void hist_kernel(const int* __restrict__ dst,
                                                   int* __restrict__ deg)
{
    int e = blockIdx.x * 256 + threadIdx.x;
    if (e < EE) atomicAdd(&deg[dst[e]], 1);
}

__global__ __launch_bounds__(1024) void scan_kernel(const int* __restrict__ deg,
                                                    int* __restrict__ rowoff)
{
    __shared__ int sd[1024];
    __shared__ int carry;
    int tid = threadIdx.x;
    if (tid == 0) carry = 0;
    __syncthreads();
    for (int base = 0; base < NN; base += 1024) {
        int i = base + tid;
        int v = (i < NN) ? deg[i] : 0;
        sd[tid] = v;
        __syncthreads();
        for (int off = 1; off < 1024; off <<= 1) {
            int t = (tid >= off) ? sd[tid - off] : 0;
            __syncthreads();
            sd[tid] += t;
            __syncthreads();
        }
        if (i < NN) rowoff[i] = carry + sd[tid] - v;   // exclusive prefix
        __syncthreads();
        if (tid == 0) carry += sd[1023];
        __syncthreads();
    }
    if (tid == 0) rowoff[NN] = carry;
}

__global__ __launch_bounds__(256) void scatter_kernel(const int* __restrict__ dst,
                                                      const int* __restrict__ rowoff,
                                                      int* __restrict__ cursor,
                                                      int* __restrict__ perm)
{
    int e = blockIdx.x * 256 + threadIdx.x;
    if (e < EE) {
        int d = dst[e];
        int pos = rowoff[d] + atomicAdd(&cursor[d], 1);
        perm[pos] = e;
    }
}

// ------------------------------------------------------------------
// Edge logits: one wave per edge; lane = channel c; loop h=0..3
// logit[e][h] = sum_c leakyrelu(xl[src][h][c]+xr[dst][h][c]+e[h][c]) * att[h][c]
// ------------------------------------------------------------------
__global__ __launch_bounds__(256) void edge_logits_kernel(
    const float* __restrict__ xl, const float* __restrict__ xr,
    const float* __restrict__ ea, const int* __restrict__ src,
    const int* __restrict__ dst, const float* __restrict__ We,
    const float* __restrict__ att, const float* __restrict__ temp,
    float* __restrict__ logit)
{
    int e = blockIdx.x * 4 + (threadIdx.x >> 6);
    int lane = threadIdx.x & 63;
    if (e >= EE) return;
    int s = src[e], d = dst[e];
    float a0 = ea[(size_t)e * 5 + 0];
    float a1 = ea[(size_t)e * 5 + 1];
    float a2 = ea[(size_t)e * 5 + 2];
    float a3 = ea[(size_t)e * 5 + 3];
    float z  = fmaxf(a3, 1e-6f);
    float a4 = temp[0] / z;               // physics: temp * 1.0 / |Z|

    float lg[4];
#pragma unroll
    for (int h = 0; h < 4; ++h) {
        int j = h * 64 + lane;
        float ev = a0 * We[j] + a1 * We[256 + j] + a2 * We[512 + j] +
                   a3 * We[768 + j] + a4 * We[1024 + j];
        float m = xl[(size_t)s * 256 + j] + xr[(size_t)d * 256 + j] + ev;
        m = (m >= 0.f) ? m : 0.2f * m;
        lg[h] = m * att[j];
    }
#pragma unroll
    for (int off = 32; off >= 1; off >>= 1) {
#pragma unroll
        for (int h = 0; h < 4; ++h) lg[h] += __shfl_xor(lg[h], off, 64);
    }
    if (lane == 0) {
        float4 o = make_float4(lg[0], lg[1], lg[2], lg[3]);
        *(float4*)(logit + (size_t)e * 4) = o;
    }
}

// ------------------------------------------------------------------
// Per-node softmax + aggregation: one wave per node, CSR over in-edges
// ------------------------------------------------------------------
__global__ __launch_bounds__(256) void node_agg_kernel(
    const int* __restrict__ rowoff, const int* __restrict__ perm,
    const float* __restrict__ logit, const float* __restrict__ xl,
    const int* __restrict__ src, const float* __restrict__ bias,
    float* __restrict__ g, int concat)
{
    int v = blockIdx.x * 4 + (threadIdx.x >> 6);
    int lane = threadIdx.x & 63;
    if (v >= NN) return;
    int beg = rowoff[v], end = rowoff[v + 1];

    float mx[4] = {-INFINITY, -INFINITY, -INFINITY, -INFINITY};
    for (int i = beg + lane; i < end; i += 64) {
        int e = perm[i];
#pragma unroll
        for (int h = 0; h < 4; ++h)
            mx[h] = fmaxf(mx[h], logit[(size_t)e * 4 + h]);
    }
#pragma unroll
    for (int off = 32; off >= 1; off >>= 1)
#pragma unroll
        for (int h = 0; h < 4; ++h)
            mx[h] = fmaxf(mx[h], __shfl_xor(mx[h], off, 64));

    float acc[4] = {0.f, 0.f, 0.f, 0.f};
    float den[4] = {0.f, 0.f, 0.f, 0.f};
    for (int i = beg; i < end; ++i) {
        int e = perm[i];
        int s = src[e];
#pragma unroll
        for (int h = 0; h < 4; ++h) {
            float w = expf(logit[(size_t)e * 4 + h] - mx[h]);
            den[h] += w;
            acc[h] += xl[(size_t)s * 256 + h * 64 + lane] * w;
        }
    }
    if (concat) {
#pragma unroll
        for (int h = 0; h < 4; ++h) {
            int j = h * 64 + lane;
            g[(size_t)v * 256 + j] = acc[h] / (den[h] + 1e-16f) + bias[j];
        }
    } else {
        float r = 0.f;
#pragma unroll
        for (int h = 0; h < 4; ++h) r += acc[h] / (den[h] + 1e-16f);
        g[(size_t)v * 64 + lane] = 0.25f * r + bias[lane];
    }
}

// ------------------------------------------------------------------
// LayerNorm(256) + residual + optional ELU; one wave per node
// ------------------------------------------------------------------
__global__ __launch_bounds__(256) void ln256_kernel(
    const float* __restrict__ gbuf, const float* __restrict__ lnw,
    const float* __restrict__ lnb, const float* __restrict__ resid,
    float* __restrict__ out, int do_elu)
{
    int v = blockIdx.x * 4 + (threadIdx.x >> 6);
    int lane = threadIdx.x & 63;
    if (v >= NN) return;
    float xv[4];
    float s = 0.f, s2 = 0.f;
#pragma unroll
    for (int k = 0; k < 4; ++k) {
        float t = gbuf[(size_t)v * 256 + k * 64 + lane];
        xv[k] = t; s += t; s2 += t * t;
    }
#pragma unroll
    for (int off = 32; off >= 1; off >>= 1) {
        s += __shfl_xor(s, off, 64);
        s2 += __shfl_xor(s2, off, 64);
    }
    float mu = s * (1.f / 256.f);
    float var = s2 * (1.f / 256.f) - mu * mu;
    float rs = rsqrtf(var + 1e-5f);
#pragma unroll
    for (int k = 0; k < 4; ++k) {
        int j = k * 64 + lane;
        float y = (xv[k] - mu) * rs * lnw[j] + lnb[j] + resid[(size_t)v * 256 + j];
        if (do_elu) y = (y > 0.f) ? y : expm1f(y);
        out[(size_t)v * 256 + j] = y;
    }
}

// LayerNorm(64) + residual (no ELU); one wave per node
__global__ __launch_bounds__(256) void ln64_kernel(
    const float* __restrict__ g64, const float* __restrict__ lnw,
    const float* __restrict__ lnb, const float* __restrict__ resid64,
    float* __restrict__ out)
{
    int v = blockIdx.x * 4 + (threadIdx.x >> 6);
    int lane = threadIdx.x & 63;
    if (v >= NN) return;
    float t = g64[(size_t)v * 64 + lane];
    float s = t, s2 = t * t;
#pragma unroll
    for (int off = 32; off >= 1; off >>= 1) {
        s += __shfl_xor(s, off, 64);
        s2 += __shfl_xor(s2, off, 64);
    }
    float mu = s * (1.f / 64.f);
    float var = s2 * (1.f / 64.f) - mu * mu;
    float rs = rsqrtf(var + 1e-5f);
    out[(size_t)v * 64 + lane] =
        (t - mu) * rs * lnw[lane] + lnb[lane] + resid64[(size_t)v * 64 + lane];
}

// ------------------------------------------------------------------
extern "C" void kernel_launch(void* const* d_in, const int* in_sizes, int n_in,
                              void* d_out, int out_size, void* d_ws, size_t ws_size,
                              hipStream_t stream)
{
    const float* x    = (const float*)d_in[0];
    const int*   eidx = (const int*)d_in[1];
    const float* ea   = (const float*)d_in[2];
    const int* src = eidx;
    const int* dst = eidx + EE;

    const float *Wl[3], *bl[3], *Wr[3], *br[3], *We[3], *att[3], *temp[3],
                *bias[3], *lnw[3], *lnb[3];
    for (int i = 0; i < 3; ++i) {
        int b = 3 + i * 10;
        Wl[i]   = (const float*)d_in[b + 0];
        bl[i]   = (const float*)d_in[b + 1];
        Wr[i]   = (const float*)d_in[b + 2];
        br[i]   = (const float*)d_in[b + 3];
        We[i]   = (const float*)d_in[b + 4];
        att[i]  = (const float*)d_in[b + 5];
        temp[i] = (const float*)d_in[b + 6];
        bias[i] = (const float*)d_in[b + 7];
        lnw[i]  = (const float*)d_in[b + 8];
        lnb[i]  = (const float*)d_in[b + 9];
    }
    const float* pw0 = (const float*)d_in[33];
    const float* pb0 = (const float*)d_in[34];
    const float* pw2 = (const float*)d_in[35];
    const float* pb2 = (const float*)d_in[36];

    // workspace carve-up
    char* w = (char*)d_ws;
    float* h     = (float*)w; w += (size_t)NN * 256 * 4;
    float* g     = (float*)w; w += (size_t)NN * 256 * 4;
    float* xl    = (float*)w; w += (size_t)NN * 256 * 4;
    float* xr    = (float*)w; w += (size_t)NN * 256 * 4;  // also reused as resid
    float* logit = (float*)w; w += (size_t)EE * 4 * 4;
    int* perm    = (int*)w;   w += (size_t)EE * 4;
    int* rowoff  = (int*)w;   w += (size_t)(NN + 1) * 4;
    int* cursor  = (int*)w;   w += (size_t)NN * 4;

    dim3 blk(256);
    dim3 grid_e((EE + 255) / 256);
    dim3 grid_ew(EE / 4);          // one wave per edge
    dim3 grid_nw((NN + 3) / 4);    // one wave per node

    auto gemm = [&](const float* A, const float* B, const float* bias_,
                    float* C, int M, int K, int NC) {
        dim3 gg((M + 127) / 128, NC / 64);
        hipLaunchKernelGGL(gemm_bias, gg, blk, 0, stream, A, B, bias_, C, M, K, NC);
    };

    // ---- CSR by dst (shared by all 3 layers) ----
    hipMemsetAsync(cursor, 0, (size_t)NN * 4, stream);
    hipLaunchKernelGGL(hist_kernel, grid_e, blk, 0, stream, dst, cursor);
    hipLaunchKernelGGL(scan_kernel, dim3(1), dim3(1024), 0, stream, cursor, rowoff);
    hipMemsetAsync(cursor, 0, (size_t)NN * 4, stream);
    hipLaunchKernelGGL(scatter_kernel, grid_e, blk, 0, stream, dst, rowoff, cursor, perm);

    // ---- Layer 0 (128 -> 256, concat) ----
    gemm(x, Wl[0], bl[0], xl, NN, 128, 256);
    gemm(x, Wr[0], br[0], xr, NN, 128, 256);
    hipLaunchKernelGGL(edge_logits_kernel, grid_ew, blk, 0, stream,
                       xl, xr, ea, src, dst, We[0], att[0], temp[0], logit);
    hipLaunchKernelGGL(node_agg_kernel, grid_nw, blk, 0, stream,
                       rowoff, perm, logit, xl, src, bias[0], g, 1);
    gemm(x, pw0, pb0, xr, NN, 128, 256);   // residual projection into xr
    hipLaunchKernelGGL(ln256_kernel, grid_nw, blk, 0, stream,
                       g, lnw[0], lnb[0], xr, h, 1);

    // ---- Layer 1 (256 -> 256, concat, identity residual) ----
    gemm(h, Wl[1], bl[1], xl, NN, 256, 256);
    gemm(h, Wr[1], br[1], xr, NN, 256, 256);
    hipLaunchKernelGGL(edge_logits_kernel, grid_ew, blk, 0, stream,
                       xl, xr, ea, src, dst, We[1], att[1], temp[1], logit);
    hipLaunchKernelGGL(node_agg_kernel, grid_nw, blk, 0, stream,
                       rowoff, perm, logit, xl, src, bias[1], g, 1);
    hipLaunchKernelGGL(ln256_kernel, grid_nw, blk, 0, stream,
                       g, lnw[1], lnb[1], h, h, 1);   // resid = h, out = h (in place)

    // ---- Layer 2 (256 -> 64, head-mean, projected residual, no ELU) ----
    gemm(h, Wl[2], bl[2], xl, NN, 256, 256);
    gemm(h, Wr[2], br[2], xr, NN, 256, 256);
    hipLaunchKernelGGL(edge_logits_kernel, grid_ew, blk, 0, stream,
                       xl, xr, ea, src, dst, We[2], att[2], temp[2], logit);
    hipLaunchKernelGGL(node_agg_kernel, grid_nw, blk, 0, stream,
                       rowoff, perm, logit, xl, src, bias[2], g, 0);
    gemm(h, pw2, pb2, xr, NN, 256, 64);    // residual projection (N x 64) into xr
    hipLaunchKernelGGL(ln64_kernel, grid_nw, blk, 0, stream,
                       g, lnw[2], lnb[2], xr, (float*)d_out);
}

// Round 2
// 2027.051 us; speedup vs baseline: 1.0782x; 1.0782x over previous
//
#include <hip/hip_runtime.h>
#include <math.h>

#define NN 50000
#define EE 800000

// ------------------------------------------------------------------
// GEMM: C[M][NC] = A[M][K] @ B[K][NC] + bias[NC]   (fp32)
// BM=128, BN=64, BK=16, block 256 threads, 8x4 micro-tile
// ------------------------------------------------------------------
__global__ __launch_bounds__(256) void gemm_bias(
    const float* __restrict__ A, const float* __restrict__ B,
    const float* __restrict__ bias, float* __restrict__ C,
    int M, int K, int NC)
{
    __shared__ float As[16][128];
    __shared__ float Bs[16][64];
    const int tid = threadIdx.x;
    const int tx = tid & 15, ty = tid >> 4;
    const int rowBase = blockIdx.x * 128;
    const int colBase = blockIdx.y * 64;

    float acc[8][4];
#pragma unroll
    for (int i = 0; i < 8; ++i)
#pragma unroll
        for (int j = 0; j < 4; ++j) acc[i][j] = 0.f;

    for (int k0 = 0; k0 < K; k0 += 16) {
#pragma unroll
        for (int l = 0; l < 2; ++l) {
            int fidx = tid * 2 + l;        // 0..511
            int r = fidx >> 2;             // 0..127
            int kq = fidx & 3;             // which float4 in the 16-k strip
            float4 v = make_float4(0.f, 0.f, 0.f, 0.f);
            int grow = rowBase + r;
            if (grow < M)
                v = *(const float4*)(A + (size_t)grow * K + k0 + kq * 4);
            As[kq * 4 + 0][r] = v.x;
            As[kq * 4 + 1][r] = v.y;
            As[kq * 4 + 2][r] = v.z;
            As[kq * 4 + 3][r] = v.w;
        }
        {
            int kb = tid >> 4, cq = tid & 15;
            *(float4*)&Bs[kb][cq * 4] =
                *(const float4*)(B + (size_t)(k0 + kb) * NC + colBase + cq * 4);
        }
        __syncthreads();
#pragma unroll
        for (int k = 0; k < 16; ++k) {
            float4 a0 = *(float4*)&As[k][ty * 8];
            float4 a1 = *(float4*)&As[k][ty * 8 + 4];
            float4 b0 = *(float4*)&Bs[k][tx * 4];
            float av[8] = {a0.x, a0.y, a0.z, a0.w, a1.x, a1.y, a1.z, a1.w};
            float bv[4] = {b0.x, b0.y, b0.z, b0.w};
#pragma unroll
            for (int i = 0; i < 8; ++i)
#pragma unroll
                for (int j = 0; j < 4; ++j)
                    acc[i][j] = fmaf(av[i], bv[j], acc[i][j]);
        }
        __syncthreads();
    }

    float4 bb = *(const float4*)(bias + colBase + tx * 4);
#pragma unroll
    for (int i = 0; i < 8; ++i) {
        int grow = rowBase + ty * 8 + i;
        if (grow >= M) continue;
        float4 o = make_float4(acc[i][0] + bb.x, acc[i][1] + bb.y,
                               acc[i][2] + bb.z, acc[i][3] + bb.w);
        *(float4*)(C + (size_t)grow * NC + colBase + tx * 4) = o;
    }
}

// ------------------------------------------------------------------
// CSR build: histogram -> scan -> scatter (also permutes src + edge attrs)
// ------------------------------------------------------------------
__global__ __launch_bounds__(256) void hist_kernel(const int* __restrict__ dst,
                                                   int* __restrict__ deg)
{
    int e = blockIdx.x * 256 + threadIdx.x;
    if (e < EE) atomicAdd(&deg[dst[e]], 1);
}

__global__ __launch_bounds__(1024) void scan_kernel(const int* __restrict__ deg,
                                                    int* __restrict__ rowoff)
{
    __shared__ int sd[1024];
    __shared__ int carry;
    int tid = threadIdx.x;
    if (tid == 0) carry = 0;
    __syncthreads();
    for (int base = 0; base < NN; base += 1024) {
        int i = base + tid;
        int v = (i < NN) ? deg[i] : 0;
        sd[tid] = v;
        __syncthreads();
        for (int off = 1; off < 1024; off <<= 1) {
            int t = (tid >= off) ? sd[tid - off] : 0;
            __syncthreads();
            sd[tid] += t;
            __syncthreads();
        }
        if (i < NN) rowoff[i] = carry + sd[tid] - v;   // exclusive prefix
        __syncthreads();
        if (tid == 0) carry += sd[1023];
        __syncthreads();
    }
    if (tid == 0) rowoff[NN] = carry;
}

__global__ __launch_bounds__(256) void scatter_kernel(
    const int* __restrict__ src, const int* __restrict__ dst,
    const float* __restrict__ ea, const int* __restrict__ rowoff,
    int* __restrict__ cursor, int* __restrict__ srcp,
    float4* __restrict__ eap)
{
    int e = blockIdx.x * 256 + threadIdx.x;
    if (e < EE) {
        int d = dst[e];
        int pos = rowoff[d] + atomicAdd(&cursor[d], 1);
        srcp[pos] = src[e];
        const float* p = ea + (size_t)e * 5;
        eap[pos] = make_float4(p[0], p[1], p[2], p[3]);
    }
}

// ------------------------------------------------------------------
// Fused per-node GATv2: logits + online softmax + aggregation.
// One wave per node; lane = channel (64), loop h = 0..3.
// Reads each xl[src] row exactly once per edge.
// ------------------------------------------------------------------
__global__ __launch_bounds__(256) void fused_attn_agg(
    const int* __restrict__ rowoff, const int* __restrict__ srcp,
    const float4* __restrict__ eap, const float* __restrict__ xl,
    const float* __restrict__ xr, const float* __restrict__ We,
    const float* __restrict__ att, const float* __restrict__ temp,
    const float* __restrict__ bias, float* __restrict__ g, int concat)
{
    int v = blockIdx.x * 4 + (threadIdx.x >> 6);
    int lane = threadIdx.x & 63;
    if (v >= NN) return;

    float we0[4], we1[4], we2[4], we3[4], we4[4], at[4], xrv[4];
#pragma unroll
    for (int h = 0; h < 4; ++h) {
        int j = h * 64 + lane;
        we0[h] = We[j];
        we1[h] = We[256 + j];
        we2[h] = We[512 + j];
        we3[h] = We[768 + j];
        we4[h] = We[1024 + j];
        at[h]  = att[j];
        xrv[h] = xr[(size_t)v * 256 + j];
    }
    float tmp = temp[0];

    float mx[4]  = {-INFINITY, -INFINITY, -INFINITY, -INFINITY};
    float den[4] = {0.f, 0.f, 0.f, 0.f};
    float acc[4] = {0.f, 0.f, 0.f, 0.f};

    int beg = rowoff[v], end = rowoff[v + 1];
    for (int i = beg; i < end; ++i) {
        int s = srcp[i];
        float4 a = eap[i];
        float a4 = tmp / fmaxf(a.w, 1e-6f);

        float lg[4], xlv[4];
#pragma unroll
        for (int h = 0; h < 4; ++h) {
            int j = h * 64 + lane;
            xlv[h] = xl[(size_t)s * 256 + j];
            float ev = a.x * we0[h] + a.y * we1[h] + a.z * we2[h] +
                       a.w * we3[h] + a4 * we4[h];
            float m = xlv[h] + xrv[h] + ev;
            m = (m >= 0.f) ? m : 0.2f * m;
            lg[h] = m * at[h];
        }
#pragma unroll
        for (int off = 32; off >= 1; off >>= 1) {
#pragma unroll
            for (int h = 0; h < 4; ++h) lg[h] += __shfl_xor(lg[h], off, 64);
        }
#pragma unroll
        for (int h = 0; h < 4; ++h) {
            float nm = fmaxf(mx[h], lg[h]);
            float sc = expf(mx[h] - nm);     // 1 when max unchanged; 0 from -inf start
            float w  = expf(lg[h] - nm);
            den[h] = den[h] * sc + w;
            acc[h] = acc[h] * sc + xlv[h] * w;
            mx[h] = nm;
        }
    }

    if (concat) {
#pragma unroll
        for (int h = 0; h < 4; ++h) {
            int j = h * 64 + lane;
            g[(size_t)v * 256 + j] = acc[h] / (den[h] + 1e-16f) + bias[j];
        }
    } else {
        float r = 0.f;
#pragma unroll
        for (int h = 0; h < 4; ++h) r += acc[h] / (den[h] + 1e-16f);
        g[(size_t)v * 64 + lane] = 0.25f * r + bias[lane];
    }
}

// ------------------------------------------------------------------
// LayerNorm(256) + residual + optional ELU; one wave per node
// ------------------------------------------------------------------
__global__ __launch_bounds__(256) void ln256_kernel(
    const float* __restrict__ gbuf, const float* __restrict__ lnw,
    const float* __restrict__ lnb, const float* __restrict__ resid,
    float* __restrict__ out, int do_elu)
{
    int v = blockIdx.x * 4 + (threadIdx.x >> 6);
    int lane = threadIdx.x & 63;
    if (v >= NN) return;
    float xv[4];
    float s = 0.f, s2 = 0.f;
#pragma unroll
    for (int k = 0; k < 4; ++k) {
        float t = gbuf[(size_t)v * 256 + k * 64 + lane];
        xv[k] = t; s += t; s2 += t * t;
    }
#pragma unroll
    for (int off = 32; off >= 1; off >>= 1) {
        s += __shfl_xor(s, off, 64);
        s2 += __shfl_xor(s2, off, 64);
    }
    float mu = s * (1.f / 256.f);
    float var = s2 * (1.f / 256.f) - mu * mu;
    float rs = rsqrtf(var + 1e-5f);
#pragma unroll
    for (int k = 0; k < 4; ++k) {
        int j = k * 64 + lane;
        float y = (xv[k] - mu) * rs * lnw[j] + lnb[j] + resid[(size_t)v * 256 + j];
        if (do_elu) y = (y > 0.f) ? y : expm1f(y);
        out[(size_t)v * 256 + j] = y;
    }
}

// LayerNorm(64) + residual (no ELU); one wave per node
__global__ __launch_bounds__(256) void ln64_kernel(
    const float* __restrict__ g64, const float* __restrict__ lnw,
    const float* __restrict__ lnb, const float* __restrict__ resid64,
    float* __restrict__ out)
{
    int v = blockIdx.x * 4 + (threadIdx.x >> 6);
    int lane = threadIdx.x & 63;
    if (v >= NN) return;
    float t = g64[(size_t)v * 64 + lane];
    float s = t, s2 = t * t;
#pragma unroll
    for (int off = 32; off >= 1; off >>= 1) {
        s += __shfl_xor(s, off, 64);
        s2 += __shfl_xor(s2, off, 64);
    }
    float mu = s * (1.f / 64.f);
    float var = s2 * (1.f / 64.f) - mu * mu;
    float rs = rsqrtf(var + 1e-5f);
    out[(size_t)v * 64 + lane] =
        (t - mu) * rs * lnw[lane] + lnb[lane] + resid64[(size_t)v * 64 + lane];
}

// ------------------------------------------------------------------
extern "C" void kernel_launch(void* const* d_in, const int* in_sizes, int n_in,
                              void* d_out, int out_size, void* d_ws, size_t ws_size,
                              hipStream_t stream)
{
    const float* x    = (const float*)d_in[0];
    const int*   eidx = (const int*)d_in[1];
    const float* ea   = (const float*)d_in[2];
    const int* src = eidx;
    const int* dst = eidx + EE;

    const float *Wl[3], *bl[3], *Wr[3], *br[3], *We[3], *att[3], *temp[3],
                *bias[3], *lnw[3], *lnb[3];
    for (int i = 0; i < 3; ++i) {
        int b = 3 + i * 10;
        Wl[i]   = (const float*)d_in[b + 0];
        bl[i]   = (const float*)d_in[b + 1];
        Wr[i]   = (const float*)d_in[b + 2];
        br[i]   = (const float*)d_in[b + 3];
        We[i]   = (const float*)d_in[b + 4];
        att[i]  = (const float*)d_in[b + 5];
        temp[i] = (const float*)d_in[b + 6];
        bias[i] = (const float*)d_in[b + 7];
        lnw[i]  = (const float*)d_in[b + 8];
        lnb[i]  = (const float*)d_in[b + 9];
    }
    const float* pw0 = (const float*)d_in[33];
    const float* pb0 = (const float*)d_in[34];
    const float* pw2 = (const float*)d_in[35];
    const float* pb2 = (const float*)d_in[36];

    // workspace carve-up
    char* w = (char*)d_ws;
    float* h     = (float*)w; w += (size_t)NN * 256 * 4;
    float* g     = (float*)w; w += (size_t)NN * 256 * 4;
    float* xl    = (float*)w; w += (size_t)NN * 256 * 4;
    float* xr    = (float*)w; w += (size_t)NN * 256 * 4;  // also reused as resid
    float4* eap  = (float4*)w; w += (size_t)EE * 16;
    int* srcp    = (int*)w;   w += (size_t)EE * 4;
    int* rowoff  = (int*)w;   w += (size_t)(NN + 1) * 4;
    int* cursor  = (int*)w;   w += (size_t)NN * 4;

    dim3 blk(256);
    dim3 grid_e((EE + 255) / 256);
    dim3 grid_nw((NN + 3) / 4);    // one wave per node

    auto gemm = [&](const float* A, const float* B, const float* bias_,
                    float* C, int M, int K, int NC) {
        dim3 gg((M + 127) / 128, NC / 64);
        hipLaunchKernelGGL(gemm_bias, gg, blk, 0, stream, A, B, bias_, C, M, K, NC);
    };

    // ---- CSR by dst (shared by all 3 layers) ----
    hipMemsetAsync(cursor, 0, (size_t)NN * 4, stream);
    hipLaunchKernelGGL(hist_kernel, grid_e, blk, 0, stream, dst, cursor);
    hipLaunchKernelGGL(scan_kernel, dim3(1), dim3(1024), 0, stream, cursor, rowoff);
    hipMemsetAsync(cursor, 0, (size_t)NN * 4, stream);
    hipLaunchKernelGGL(scatter_kernel, grid_e, blk, 0, stream,
                       src, dst, ea, rowoff, cursor, srcp, eap);

    // ---- Layer 0 (128 -> 256, concat) ----
    gemm(x, Wl[0], bl[0], xl, NN, 128, 256);
    gemm(x, Wr[0], br[0], xr, NN, 128, 256);
    hipLaunchKernelGGL(fused_attn_agg, grid_nw, blk, 0, stream,
                       rowoff, srcp, eap, xl, xr, We[0], att[0], temp[0],
                       bias[0], g, 1);
    gemm(x, pw0, pb0, xr, NN, 128, 256);   // residual projection into xr
    hipLaunchKernelGGL(ln256_kernel, grid_nw, blk, 0, stream,
                       g, lnw[0], lnb[0], xr, h, 1);

    // ---- Layer 1 (256 -> 256, concat, identity residual) ----
    gemm(h, Wl[1], bl[1], xl, NN, 256, 256);
    gemm(h, Wr[1], br[1], xr, NN, 256, 256);
    hipLaunchKernelGGL(fused_attn_agg, grid_nw, blk, 0, stream,
                       rowoff, srcp, eap, xl, xr, We[1], att[1], temp[1],
                       bias[1], g, 1);
    hipLaunchKernelGGL(ln256_kernel, grid_nw, blk, 0, stream,
                       g, lnw[1], lnb[1], h, h, 1);   // resid = h, out = h (in place)

    // ---- Layer 2 (256 -> 64, head-mean, projected residual, no ELU) ----
    gemm(h, Wl[2], bl[2], xl, NN, 256, 256);
    gemm(h, Wr[2], br[2], xr, NN, 256, 256);
    hipLaunchKernelGGL(fused_attn_agg, grid_nw, blk, 0, stream,
                       rowoff, srcp, eap, xl, xr, We[2], att[2], temp[2],
                       bias[2], g, 0);
    gemm(h, pw2, pb2, xr, NN, 256, 64);    // residual projection (N x 64) into xr
    hipLaunchKernelGGL(ln64_kernel, grid_nw, blk, 0, stream,
                       g, lnw[2], lnb[2], xr, (float*)d_out);
}

// Round 3
// 1455.841 us; speedup vs baseline: 1.5012x; 1.3924x over previous
//
#include <hip/hip_runtime.h>
#include <math.h>

#define NN 50000
#define EE 800000

// ------------------------------------------------------------------
// GEMM 128x128 tile, BK=16, 256 threads, 8x8 micro-tile (fp32)
// ------------------------------------------------------------------
__global__ __launch_bounds__(256) void gemm128(
    const float* __restrict__ A, const float* __restrict__ B,
    const float* __restrict__ bias, float* __restrict__ C,
    int M, int K, int NC)
{
    __shared__ float As[16][128];
    __shared__ float Bs[16][128];
    const int tid = threadIdx.x;
    const int tx = tid & 15, ty = tid >> 4;
    const int rowBase = blockIdx.x * 128;
    const int colBase = blockIdx.y * 128;

    float acc[8][8];
#pragma unroll
    for (int i = 0; i < 8; ++i)
#pragma unroll
        for (int j = 0; j < 8; ++j) acc[i][j] = 0.f;

    for (int k0 = 0; k0 < K; k0 += 16) {
#pragma unroll
        for (int l = 0; l < 2; ++l) {
            int fidx = tid * 2 + l;        // 0..511
            int r = fidx >> 2;             // 0..127
            int q = fidx & 3;              // float4 within 16-k strip
            float4 v = make_float4(0.f, 0.f, 0.f, 0.f);
            int grow = rowBase + r;
            if (grow < M)
                v = *(const float4*)(A + (size_t)grow * K + k0 + q * 4);
            As[q * 4 + 0][r] = v.x;
            As[q * 4 + 1][r] = v.y;
            As[q * 4 + 2][r] = v.z;
            As[q * 4 + 3][r] = v.w;
        }
#pragma unroll
        for (int l = 0; l < 2; ++l) {
            int fidx = tid * 2 + l;        // 0..511
            int kb = fidx >> 5;            // 0..15
            int cq = fidx & 31;            // 0..31
            *(float4*)&Bs[kb][cq * 4] =
                *(const float4*)(B + (size_t)(k0 + kb) * NC + colBase + cq * 4);
        }
        __syncthreads();
#pragma unroll
        for (int k = 0; k < 16; ++k) {
            float4 a0 = *(float4*)&As[k][ty * 8];
            float4 a1 = *(float4*)&As[k][ty * 8 + 4];
            float4 b0 = *(float4*)&Bs[k][tx * 8];
            float4 b1 = *(float4*)&Bs[k][tx * 8 + 4];
            float av[8] = {a0.x, a0.y, a0.z, a0.w, a1.x, a1.y, a1.z, a1.w};
            float bv[8] = {b0.x, b0.y, b0.z, b0.w, b1.x, b1.y, b1.z, b1.w};
#pragma unroll
            for (int i = 0; i < 8; ++i)
#pragma unroll
                for (int j = 0; j < 8; ++j)
                    acc[i][j] = fmaf(av[i], bv[j], acc[i][j]);
        }
        __syncthreads();
    }

    float4 bb0 = *(const float4*)(bias + colBase + tx * 8);
    float4 bb1 = *(const float4*)(bias + colBase + tx * 8 + 4);
#pragma unroll
    for (int i = 0; i < 8; ++i) {
        int grow = rowBase + ty * 8 + i;
        if (grow >= M) continue;
        float4 o0 = make_float4(acc[i][0] + bb0.x, acc[i][1] + bb0.y,
                                acc[i][2] + bb0.z, acc[i][3] + bb0.w);
        float4 o1 = make_float4(acc[i][4] + bb1.x, acc[i][5] + bb1.y,
                                acc[i][6] + bb1.z, acc[i][7] + bb1.w);
        *(float4*)(C + (size_t)grow * NC + colBase + tx * 8) = o0;
        *(float4*)(C + (size_t)grow * NC + colBase + tx * 8 + 4) = o1;
    }
}

// ------------------------------------------------------------------
// GEMM: BM=128, BN=64 (for the final 256->64 projection)
// ------------------------------------------------------------------
__global__ __launch_bounds__(256) void gemm_bias(
    const float* __restrict__ A, const float* __restrict__ B,
    const float* __restrict__ bias, float* __restrict__ C,
    int M, int K, int NC)
{
    __shared__ float As[16][128];
    __shared__ float Bs[16][64];
    const int tid = threadIdx.x;
    const int tx = tid & 15, ty = tid >> 4;
    const int rowBase = blockIdx.x * 128;
    const int colBase = blockIdx.y * 64;

    float acc[8][4];
#pragma unroll
    for (int i = 0; i < 8; ++i)
#pragma unroll
        for (int j = 0; j < 4; ++j) acc[i][j] = 0.f;

    for (int k0 = 0; k0 < K; k0 += 16) {
#pragma unroll
        for (int l = 0; l < 2; ++l) {
            int fidx = tid * 2 + l;
            int r = fidx >> 2;
            int q = fidx & 3;
            float4 v = make_float4(0.f, 0.f, 0.f, 0.f);
            int grow = rowBase + r;
            if (grow < M)
                v = *(const float4*)(A + (size_t)grow * K + k0 + q * 4);
            As[q * 4 + 0][r] = v.x;
            As[q * 4 + 1][r] = v.y;
            As[q * 4 + 2][r] = v.z;
            As[q * 4 + 3][r] = v.w;
        }
        {
            int kb = tid >> 4, cq = tid & 15;
            *(float4*)&Bs[kb][cq * 4] =
                *(const float4*)(B + (size_t)(k0 + kb) * NC + colBase + cq * 4);
        }
        __syncthreads();
#pragma unroll
        for (int k = 0; k < 16; ++k) {
            float4 a0 = *(float4*)&As[k][ty * 8];
            float4 a1 = *(float4*)&As[k][ty * 8 + 4];
            float4 b0 = *(float4*)&Bs[k][tx * 4];
            float av[8] = {a0.x, a0.y, a0.z, a0.w, a1.x, a1.y, a1.z, a1.w};
            float bv[4] = {b0.x, b0.y, b0.z, b0.w};
#pragma unroll
            for (int i = 0; i < 8; ++i)
#pragma unroll
                for (int j = 0; j < 4; ++j)
                    acc[i][j] = fmaf(av[i], bv[j], acc[i][j]);
        }
        __syncthreads();
    }

    float4 bb = *(const float4*)(bias + colBase + tx * 4);
#pragma unroll
    for (int i = 0; i < 8; ++i) {
        int grow = rowBase + ty * 8 + i;
        if (grow >= M) continue;
        float4 o = make_float4(acc[i][0] + bb.x, acc[i][1] + bb.y,
                               acc[i][2] + bb.z, acc[i][3] + bb.w);
        *(float4*)(C + (size_t)grow * NC + colBase + tx * 4) = o;
    }
}

// ------------------------------------------------------------------
// CSR build: histogram -> scan -> scatter (permutes src, attrs; precomputes 1/z)
// ------------------------------------------------------------------
__global__ __launch_bounds__(256) void hist_kernel(const int* __restrict__ dst,
                                                   int* __restrict__ deg)
{
    int e = blockIdx.x * 256 + threadIdx.x;
    if (e < EE) atomicAdd(&deg[dst[e]], 1);
}

__global__ __launch_bounds__(1024) void scan_kernel(const int* __restrict__ deg,
                                                    int* __restrict__ rowoff)
{
    __shared__ int sd[1024];
    __shared__ int carry;
    int tid = threadIdx.x;
    if (tid == 0) carry = 0;
    __syncthreads();
    for (int base = 0; base < NN; base += 1024) {
        int i = base + tid;
        int v = (i < NN) ? deg[i] : 0;
        sd[tid] = v;
        __syncthreads();
        for (int off = 1; off < 1024; off <<= 1) {
            int t = (tid >= off) ? sd[tid - off] : 0;
            __syncthreads();
            sd[tid] += t;
            __syncthreads();
        }
        if (i < NN) rowoff[i] = carry + sd[tid] - v;
        __syncthreads();
        if (tid == 0) carry += sd[1023];
        __syncthreads();
    }
    if (tid == 0) rowoff[NN] = carry;
}

__global__ __launch_bounds__(256) void scatter_kernel(
    const int* __restrict__ src, const int* __restrict__ dst,
    const float* __restrict__ ea, const int* __restrict__ rowoff,
    int* __restrict__ cursor, int* __restrict__ srcp,
    float4* __restrict__ eap, float* __restrict__ erec)
{
    int e = blockIdx.x * 256 + threadIdx.x;
    if (e < EE) {
        int d = dst[e];
        int pos = rowoff[d] + atomicAdd(&cursor[d], 1);
        srcp[pos] = src[e];
        const float* p = ea + (size_t)e * 5;
        eap[pos] = make_float4(p[0], p[1], p[2], p[3]);
        erec[pos] = 1.0f / fmaxf(p[3], 1e-6f);   // hoisted division
    }
}

// ------------------------------------------------------------------
// Fused per-node GATv2: logits + online softmax (base-2) + aggregation.
// One wave per node. Head-major lanes: grp=lane>>4 is the head, each
// lane owns 4 consecutive channels -> float4 gathers, 16-lane butterfly,
// no cross-head broadcast of softmax state.
// ------------------------------------------------------------------
__global__ __launch_bounds__(256) void fused_attn_agg(
    const int* __restrict__ rowoff, const int* __restrict__ srcp,
    const float4* __restrict__ eap, const float* __restrict__ erec,
    const float* __restrict__ xl, const float* __restrict__ xr,
    const float* __restrict__ We, const float* __restrict__ att,
    const float* __restrict__ temp, const float* __restrict__ bias,
    float* __restrict__ g, int concat)
{
    int v = blockIdx.x * 4 + (threadIdx.x >> 6);
    int lane = threadIdx.x & 63;
    if (v >= NN) return;
    int grp = lane >> 4;                 // head
    int sub = lane & 15;
    int j = grp * 64 + sub * 4;          // first of this lane's 4 channels

    float4 w0 = *(const float4*)(We + j);
    float4 w1 = *(const float4*)(We + 256 + j);
    float4 w2 = *(const float4*)(We + 512 + j);
    float4 w3 = *(const float4*)(We + 768 + j);
    float4 w4 = *(const float4*)(We + 1024 + j);
    float4 at = *(const float4*)(att + j);
    float4 xrv = *(const float4*)(xr + (size_t)v * 256 + j);
    float tmp = temp[0];
    const float L2E = 1.44269504088896340736f;

    float mxd = -INFINITY, dend = 0.f;
    float4 acc = make_float4(0.f, 0.f, 0.f, 0.f);

    int beg = rowoff[v], end = rowoff[v + 1];
    for (int i = beg; i < end; ++i) {
        int s = srcp[i];
        float4 a = eap[i];
        float a4 = tmp * erec[i];
        float4 xlv = *(const float4*)(xl + (size_t)s * 256 + j);

        float m0 = fmaf(a.x, w0.x, fmaf(a.y, w1.x, fmaf(a.z, w2.x,
                   fmaf(a.w, w3.x, fmaf(a4, w4.x, xlv.x + xrv.x)))));
        float m1 = fmaf(a.x, w0.y, fmaf(a.y, w1.y, fmaf(a.z, w2.y,
                   fmaf(a.w, w3.y, fmaf(a4, w4.y, xlv.y + xrv.y)))));
        float m2 = fmaf(a.x, w0.z, fmaf(a.y, w1.z, fmaf(a.z, w2.z,
                   fmaf(a.w, w3.z, fmaf(a4, w4.z, xlv.z + xrv.z)))));
        float m3 = fmaf(a.x, w0.w, fmaf(a.y, w1.w, fmaf(a.z, w2.w,
                   fmaf(a.w, w3.w, fmaf(a4, w4.w, xlv.w + xrv.w)))));
        // leaky_relu(m, 0.2) == max(m, 0.2*m) for slope in (0,1)
        m0 = fmaxf(m0, 0.2f * m0);
        m1 = fmaxf(m1, 0.2f * m1);
        m2 = fmaxf(m2, 0.2f * m2);
        m3 = fmaxf(m3, 0.2f * m3);
        float lg = fmaf(m3, at.w, fmaf(m2, at.z, fmaf(m1, at.y, m0 * at.x)));
        // 16-lane butterfly within the head group
        lg += __shfl_xor(lg, 8, 64);
        lg += __shfl_xor(lg, 4, 64);
        lg += __shfl_xor(lg, 2, 64);
        lg += __shfl_xor(lg, 1, 64);
        // online softmax in base-2 (lane's own head state; no broadcast)
        float l2 = lg * L2E;
        float nm = fmaxf(mxd, l2);
        float sc = exp2f(mxd - nm);
        float w  = exp2f(l2 - nm);
        dend = fmaf(dend, sc, w);
        mxd = nm;
        acc.x = fmaf(acc.x, sc, xlv.x * w);
        acc.y = fmaf(acc.y, sc, xlv.y * w);
        acc.z = fmaf(acc.z, sc, xlv.z * w);
        acc.w = fmaf(acc.w, sc, xlv.w * w);
    }

    float inv = 1.f / (dend + 1e-16f);
    if (concat) {
        float4 bb = *(const float4*)(bias + j);
        float4 o = make_float4(fmaf(acc.x, inv, bb.x), fmaf(acc.y, inv, bb.y),
                               fmaf(acc.z, inv, bb.z), fmaf(acc.w, inv, bb.w));
        *(float4*)(g + (size_t)v * 256 + j) = o;
    } else {
        float4 r = make_float4(acc.x * inv, acc.y * inv, acc.z * inv, acc.w * inv);
        r.x += __shfl_xor(r.x, 16, 64); r.x += __shfl_xor(r.x, 32, 64);
        r.y += __shfl_xor(r.y, 16, 64); r.y += __shfl_xor(r.y, 32, 64);
        r.z += __shfl_xor(r.z, 16, 64); r.z += __shfl_xor(r.z, 32, 64);
        r.w += __shfl_xor(r.w, 16, 64); r.w += __shfl_xor(r.w, 32, 64);
        if (grp == 0) {
            float4 bb = *(const float4*)(bias + sub * 4);
            float4 o = make_float4(fmaf(r.x, 0.25f, bb.x), fmaf(r.y, 0.25f, bb.y),
                                   fmaf(r.z, 0.25f, bb.z), fmaf(r.w, 0.25f, bb.w));
            *(float4*)(g + (size_t)v * 64 + sub * 4) = o;
        }
    }
}

// ------------------------------------------------------------------
// LayerNorm(256) + residual + optional ELU; one wave per node
// ------------------------------------------------------------------
__global__ __launch_bounds__(256) void ln256_kernel(
    const float* __restrict__ gbuf, const float* __restrict__ lnw,
    const float* __restrict__ lnb, const float* __restrict__ resid,
    float* __restrict__ out, int do_elu)
{
    int v = blockIdx.x * 4 + (threadIdx.x >> 6);
    int lane = threadIdx.x & 63;
    if (v >= NN) return;
    float xv[4];
    float s = 0.f, s2 = 0.f;
#pragma unroll
    for (int k = 0; k < 4; ++k) {
        float t = gbuf[(size_t)v * 256 + k * 64 + lane];
        xv[k] = t; s += t; s2 += t * t;
    }
#pragma unroll
    for (int off = 32; off >= 1; off >>= 1) {
        s += __shfl_xor(s, off, 64);
        s2 += __shfl_xor(s2, off, 64);
    }
    float mu = s * (1.f / 256.f);
    float var = s2 * (1.f / 256.f) - mu * mu;
    float rs = rsqrtf(var + 1e-5f);
#pragma unroll
    for (int k = 0; k < 4; ++k) {
        int j = k * 64 + lane;
        float y = (xv[k] - mu) * rs * lnw[j] + lnb[j] + resid[(size_t)v * 256 + j];
        if (do_elu) y = (y > 0.f) ? y : expm1f(y);
        out[(size_t)v * 256 + j] = y;
    }
}

__global__ __launch_bounds__(256) void ln64_kernel(
    const float* __restrict__ g64, const float* __restrict__ lnw,
    const float* __restrict__ lnb, const float* __restrict__ resid64,
    float* __restrict__ out)
{
    int v = blockIdx.x * 4 + (threadIdx.x >> 6);
    int lane = threadIdx.x & 63;
    if (v >= NN) return;
    float t = g64[(size_t)v * 64 + lane];
    float s = t, s2 = t * t;
#pragma unroll
    for (int off = 32; off >= 1; off >>= 1) {
        s += __shfl_xor(s, off, 64);
        s2 += __shfl_xor(s2, off, 64);
    }
    float mu = s * (1.f / 64.f);
    float var = s2 * (1.f / 64.f) - mu * mu;
    float rs = rsqrtf(var + 1e-5f);
    out[(size_t)v * 64 + lane] =
        (t - mu) * rs * lnw[lane] + lnb[lane] + resid64[(size_t)v * 64 + lane];
}

// ------------------------------------------------------------------
extern "C" void kernel_launch(void* const* d_in, const int* in_sizes, int n_in,
                              void* d_out, int out_size, void* d_ws, size_t ws_size,
                              hipStream_t stream)
{
    const float* x    = (const float*)d_in[0];
    const int*   eidx = (const int*)d_in[1];
    const float* ea   = (const float*)d_in[2];
    const int* src = eidx;
    const int* dst = eidx + EE;

    const float *Wl[3], *bl[3], *Wr[3], *br[3], *We[3], *att[3], *temp[3],
                *bias[3], *lnw[3], *lnb[3];
    for (int i = 0; i < 3; ++i) {
        int b = 3 + i * 10;
        Wl[i]   = (const float*)d_in[b + 0];
        bl[i]   = (const float*)d_in[b + 1];
        Wr[i]   = (const float*)d_in[b + 2];
        br[i]   = (const float*)d_in[b + 3];
        We[i]   = (const float*)d_in[b + 4];
        att[i]  = (const float*)d_in[b + 5];
        temp[i] = (const float*)d_in[b + 6];
        bias[i] = (const float*)d_in[b + 7];
        lnw[i]  = (const float*)d_in[b + 8];
        lnb[i]  = (const float*)d_in[b + 9];
    }
    const float* pw0 = (const float*)d_in[33];
    const float* pb0 = (const float*)d_in[34];
    const float* pw2 = (const float*)d_in[35];
    const float* pb2 = (const float*)d_in[36];

    // workspace carve-up
    char* w = (char*)d_ws;
    float* h     = (float*)w; w += (size_t)NN * 256 * 4;
    float* g     = (float*)w; w += (size_t)NN * 256 * 4;
    float* xl    = (float*)w; w += (size_t)NN * 256 * 4;
    float* xr    = (float*)w; w += (size_t)NN * 256 * 4;
    float4* eap  = (float4*)w; w += (size_t)EE * 16;
    float* erec  = (float*)w; w += (size_t)EE * 4;
    int* srcp    = (int*)w;   w += (size_t)EE * 4;
    int* rowoff  = (int*)w;   w += (size_t)(NN + 1) * 4;
    int* cursor  = (int*)w;   w += (size_t)NN * 4;

    dim3 blk(256);
    dim3 grid_e((EE + 255) / 256);
    dim3 grid_nw((NN + 3) / 4);

    auto gemm = [&](const float* A, const float* B, const float* bias_,
                    float* C, int M, int K, int NC) {
        if (NC % 128 == 0) {
            dim3 gg((M + 127) / 128, NC / 128);
            hipLaunchKernelGGL(gemm128, gg, blk, 0, stream, A, B, bias_, C, M, K, NC);
        } else {
            dim3 gg((M + 127) / 128, NC / 64);
            hipLaunchKernelGGL(gemm_bias, gg, blk, 0, stream, A, B, bias_, C, M, K, NC);
        }
    };

    // ---- CSR by dst (shared by all 3 layers) ----
    hipMemsetAsync(cursor, 0, (size_t)NN * 4, stream);
    hipLaunchKernelGGL(hist_kernel, grid_e, blk, 0, stream, dst, cursor);
    hipLaunchKernelGGL(scan_kernel, dim3(1), dim3(1024), 0, stream, cursor, rowoff);
    hipMemsetAsync(cursor, 0, (size_t)NN * 4, stream);
    hipLaunchKernelGGL(scatter_kernel, grid_e, blk, 0, stream,
                       src, dst, ea, rowoff, cursor, srcp, eap, erec);

    // ---- Layer 0 (128 -> 256, concat) ----
    gemm(x, Wl[0], bl[0], xl, NN, 128, 256);
    gemm(x, Wr[0], br[0], xr, NN, 128, 256);
    hipLaunchKernelGGL(fused_attn_agg, grid_nw, blk, 0, stream,
                       rowoff, srcp, eap, erec, xl, xr, We[0], att[0], temp[0],
                       bias[0], g, 1);
    gemm(x, pw0, pb0, xr, NN, 128, 256);
    hipLaunchKernelGGL(ln256_kernel, grid_nw, blk, 0, stream,
                       g, lnw[0], lnb[0], xr, h, 1);

    // ---- Layer 1 (256 -> 256, concat, identity residual) ----
    gemm(h, Wl[1], bl[1], xl, NN, 256, 256);
    gemm(h, Wr[1], br[1], xr, NN, 256, 256);
    hipLaunchKernelGGL(fused_attn_agg, grid_nw, blk, 0, stream,
                       rowoff, srcp, eap, erec, xl, xr, We[1], att[1], temp[1],
                       bias[1], g, 1);
    hipLaunchKernelGGL(ln256_kernel, grid_nw, blk, 0, stream,
                       g, lnw[1], lnb[1], h, h, 1);

    // ---- Layer 2 (256 -> 64, head-mean, projected residual, no ELU) ----
    gemm(h, Wl[2], bl[2], xl, NN, 256, 256);
    gemm(h, Wr[2], br[2], xr, NN, 256, 256);
    hipLaunchKernelGGL(fused_attn_agg, grid_nw, blk, 0, stream,
                       rowoff, srcp, eap, erec, xl, xr, We[2], att[2], temp[2],
                       bias[2], g, 0);
    gemm(h, pw2, pb2, xr, NN, 256, 64);
    hipLaunchKernelGGL(ln64_kernel, grid_nw, blk, 0, stream,
                       g, lnw[2], lnb[2], xr, (float*)d_out);
}

// Round 4
// 1133.224 us; speedup vs baseline: 1.9286x; 1.2847x over previous
//
#include <hip/hip_runtime.h>
#include <math.h>

#define NN 50000
#define EE 800000

typedef _Float16 half8 __attribute__((ext_vector_type(8)));
typedef float floatx16 __attribute__((ext_vector_type(16)));

// ------------------------------------------------------------------
// Swizzle A (fp32 row-major M x K) into 32x32x16 MFMA A-fragment order:
// Asw[tile][kc][lane][j] halves, lane = (m&31) + 32*(k-half), j = k&7.
// One wave per (tile, kc). Rows >= M zero-filled.
// ------------------------------------------------------------------
__global__ __launch_bounds__(256) void swizzleA(
    const float* __restrict__ A, _Float16* __restrict__ Asw, int M, int K)
{
    int wave = threadIdx.x >> 6, lane = threadIdx.x & 63;
    int tile = blockIdx.x;
    int kc = blockIdx.y * 4 + wave;
    int KC = K >> 4;
    int row = tile * 32 + (lane & 31);
    int k0 = kc * 16 + (lane >> 5) * 8;
    float4 v0 = make_float4(0.f, 0.f, 0.f, 0.f);
    float4 v1 = make_float4(0.f, 0.f, 0.f, 0.f);
    if (row < M) {
        const float* p = A + (size_t)row * K + k0;
        v0 = *(const float4*)p;
        v1 = *(const float4*)(p + 4);
    }
    half8 o;
    o[0] = (_Float16)v0.x; o[1] = (_Float16)v0.y;
    o[2] = (_Float16)v0.z; o[3] = (_Float16)v0.w;
    o[4] = (_Float16)v1.x; o[5] = (_Float16)v1.y;
    o[6] = (_Float16)v1.z; o[7] = (_Float16)v1.w;
    *(half8*)(Asw + (((size_t)tile * KC + kc) * 64 + lane) * 8) = o;
}

// ------------------------------------------------------------------
// Swizzle B (fp32 K x NC) into B-fragment order:
// Bsw[ntile][kc][lane][j], lane = (n&31) + 32*(k-half), j = k&7.
// ------------------------------------------------------------------
__global__ __launch_bounds__(256) void swizzleB(
    const float* __restrict__ B, _Float16* __restrict__ Bsw, int K, int NC)
{
    int wave = threadIdx.x >> 6, lane = threadIdx.x & 63;
    int KC = K >> 4, NT = NC >> 5;
    int pair = blockIdx.x * 4 + wave;       // pair = nt*KC + kc
    if (pair >= NT * KC) return;
    int nt = pair / KC, kc = pair - nt * KC;
    int n = nt * 32 + (lane & 31);
    int k0 = kc * 16 + (lane >> 5) * 8;
    half8 o;
#pragma unroll
    for (int j = 0; j < 8; ++j)
        o[j] = (_Float16)B[(size_t)(k0 + j) * NC + n];
    *(half8*)(Bsw + ((size_t)pair * 64 + lane) * 8) = o;
}

// ------------------------------------------------------------------
// MFMA GEMM: C = A @ B + bias, fp16 inputs (pre-swizzled), fp32 accum.
// Block = 4 waves; wave computes 64 rows x (CT*32) cols via 32x32x16 MFMA.
// Block tile: 128 rows x (2*CT*32) cols. No LDS, no barriers.
// ------------------------------------------------------------------
template<int CT>
__global__ __launch_bounds__(256) void gemm_mfma(
    const _Float16* __restrict__ Asw, const _Float16* __restrict__ Bsw,
    const float* __restrict__ bias, float* __restrict__ C,
    int M, int K, int NC)
{
    const int wave = threadIdx.x >> 6, lane = threadIdx.x & 63;
    const int KC = K >> 4;
    const int rt0 = blockIdx.x * 4 + (wave & 1) * 2;
    const int ct0 = blockIdx.y * (2 * CT) + (wave >> 1) * CT;

    const half8* Ap0 = (const half8*)Asw + (size_t)rt0 * KC * 64 + lane;
    const half8* Ap1 = Ap0 + (size_t)KC * 64;
    const half8* Bp0 = (const half8*)Bsw + (size_t)ct0 * KC * 64 + lane;
    const half8* Bp1 = Bp0 + (size_t)KC * 64;

    floatx16 acc00 = {0.f}, acc10 = {0.f}, acc01 = {0.f}, acc11 = {0.f};

    for (int kc = 0; kc < KC; ++kc) {
        half8 a0 = Ap0[(size_t)kc * 64];
        half8 a1 = Ap1[(size_t)kc * 64];
        half8 b0 = Bp0[(size_t)kc * 64];
        acc00 = __builtin_amdgcn_mfma_f32_32x32x16_f16(a0, b0, acc00, 0, 0, 0);
        acc10 = __builtin_amdgcn_mfma_f32_32x32x16_f16(a1, b0, acc10, 0, 0, 0);
        if (CT == 2) {
            half8 b1 = Bp1[(size_t)kc * 64];
            acc01 = __builtin_amdgcn_mfma_f32_32x32x16_f16(a0, b1, acc01, 0, 0, 0);
            acc11 = __builtin_amdgcn_mfma_f32_32x32x16_f16(a1, b1, acc11, 0, 0, 0);
        }
    }

    const int nlane = lane & 31, hs = lane >> 5;
#pragma unroll
    for (int c = 0; c < CT; ++c) {
        int col = (ct0 + c) * 32 + nlane;
        float bb = bias[col];
        const floatx16& a_ = (c == 0) ? acc00 : acc01;   // row-tile rt0
        const floatx16& b_ = (c == 0) ? acc10 : acc11;   // row-tile rt0+1
#pragma unroll
        for (int r = 0; r < 16; ++r) {
            int rowin = (r & 3) + 8 * (r >> 2) + 4 * hs;
            int row0 = rt0 * 32 + rowin;
            int row1 = row0 + 32;
            if (row0 < M) C[(size_t)row0 * NC + col] = a_[r] + bb;
            if (row1 < M) C[(size_t)row1 * NC + col] = b_[r] + bb;
        }
    }
}

// ------------------------------------------------------------------
// CSR build: histogram -> scan -> scatter (permutes src, attrs; precomputes 1/z)
// ------------------------------------------------------------------
__global__ __launch_bounds__(256) void hist_kernel(const int* __restrict__ dst,
                                                   int* __restrict__ deg)
{
    int e = blockIdx.x * 256 + threadIdx.x;
    if (e < EE) atomicAdd(&deg[dst[e]], 1);
}

__global__ __launch_bounds__(1024) void scan_kernel(const int* __restrict__ deg,
                                                    int* __restrict__ rowoff)
{
    __shared__ int sd[1024];
    __shared__ int carry;
    int tid = threadIdx.x;
    if (tid == 0) carry = 0;
    __syncthreads();
    for (int base = 0; base < NN; base += 1024) {
        int i = base + tid;
        int v = (i < NN) ? deg[i] : 0;
        sd[tid] = v;
        __syncthreads();
        for (int off = 1; off < 1024; off <<= 1) {
            int t = (tid >= off) ? sd[tid - off] : 0;
            __syncthreads();
            sd[tid] += t;
            __syncthreads();
        }
        if (i < NN) rowoff[i] = carry + sd[tid] - v;
        __syncthreads();
        if (tid == 0) carry += sd[1023];
        __syncthreads();
    }
    if (tid == 0) rowoff[NN] = carry;
}

__global__ __launch_bounds__(256) void scatter_kernel(
    const int* __restrict__ src, const int* __restrict__ dst,
    const float* __restrict__ ea, const int* __restrict__ rowoff,
    int* __restrict__ cursor, int* __restrict__ srcp,
    float4* __restrict__ eap, float* __restrict__ erec)
{
    int e = blockIdx.x * 256 + threadIdx.x;
    if (e < EE) {
        int d = dst[e];
        int pos = rowoff[d] + atomicAdd(&cursor[d], 1);
        srcp[pos] = src[e];
        const float* p = ea + (size_t)e * 5;
        eap[pos] = make_float4(p[0], p[1], p[2], p[3]);
        erec[pos] = 1.0f / fmaxf(p[3], 1e-6f);   // hoisted division
    }
}

// ------------------------------------------------------------------
// Fused per-node GATv2: logits + online softmax (base-2) + aggregation.
// ------------------------------------------------------------------
__global__ __launch_bounds__(256) void fused_attn_agg(
    const int* __restrict__ rowoff, const int* __restrict__ srcp,
    const float4* __restrict__ eap, const float* __restrict__ erec,
    const float* __restrict__ xl, const float* __restrict__ xr,
    const float* __restrict__ We, const float* __restrict__ att,
    const float* __restrict__ temp, const float* __restrict__ bias,
    float* __restrict__ g, int concat)
{
    int v = blockIdx.x * 4 + (threadIdx.x >> 6);
    int lane = threadIdx.x & 63;
    if (v >= NN) return;
    int grp = lane >> 4;                 // head
    int sub = lane & 15;
    int j = grp * 64 + sub * 4;          // first of this lane's 4 channels

    float4 w0 = *(const float4*)(We + j);
    float4 w1 = *(const float4*)(We + 256 + j);
    float4 w2 = *(const float4*)(We + 512 + j);
    float4 w3 = *(const float4*)(We + 768 + j);
    float4 w4 = *(const float4*)(We + 1024 + j);
    float4 at = *(const float4*)(att + j);
    float4 xrv = *(const float4*)(xr + (size_t)v * 256 + j);
    float tmp = temp[0];
    const float L2E = 1.44269504088896340736f;

    float mxd = -INFINITY, dend = 0.f;
    float4 acc = make_float4(0.f, 0.f, 0.f, 0.f);

    int beg = rowoff[v], end = rowoff[v + 1];
    for (int i = beg; i < end; ++i) {
        int s = srcp[i];
        float4 a = eap[i];
        float a4 = tmp * erec[i];
        float4 xlv = *(const float4*)(xl + (size_t)s * 256 + j);

        float m0 = fmaf(a.x, w0.x, fmaf(a.y, w1.x, fmaf(a.z, w2.x,
                   fmaf(a.w, w3.x, fmaf(a4, w4.x, xlv.x + xrv.x)))));
        float m1 = fmaf(a.x, w0.y, fmaf(a.y, w1.y, fmaf(a.z, w2.y,
                   fmaf(a.w, w3.y, fmaf(a4, w4.y, xlv.y + xrv.y)))));
        float m2 = fmaf(a.x, w0.z, fmaf(a.y, w1.z, fmaf(a.z, w2.z,
                   fmaf(a.w, w3.z, fmaf(a4, w4.z, xlv.z + xrv.z)))));
        float m3 = fmaf(a.x, w0.w, fmaf(a.y, w1.w, fmaf(a.z, w2.w,
                   fmaf(a.w, w3.w, fmaf(a4, w4.w, xlv.w + xrv.w)))));
        m0 = fmaxf(m0, 0.2f * m0);
        m1 = fmaxf(m1, 0.2f * m1);
        m2 = fmaxf(m2, 0.2f * m2);
        m3 = fmaxf(m3, 0.2f * m3);
        float lg = fmaf(m3, at.w, fmaf(m2, at.z, fmaf(m1, at.y, m0 * at.x)));
        lg += __shfl_xor(lg, 8, 64);
        lg += __shfl_xor(lg, 4, 64);
        lg += __shfl_xor(lg, 2, 64);
        lg += __shfl_xor(lg, 1, 64);
        float l2 = lg * L2E;
        float nm = fmaxf(mxd, l2);
        float sc = exp2f(mxd - nm);
        float w  = exp2f(l2 - nm);
        dend = fmaf(dend, sc, w);
        mxd = nm;
        acc.x = fmaf(acc.x, sc, xlv.x * w);
        acc.y = fmaf(acc.y, sc, xlv.y * w);
        acc.z = fmaf(acc.z, sc, xlv.z * w);
        acc.w = fmaf(acc.w, sc, xlv.w * w);
    }

    float inv = 1.f / (dend + 1e-16f);
    if (concat) {
        float4 bb = *(const float4*)(bias + j);
        float4 o = make_float4(fmaf(acc.x, inv, bb.x), fmaf(acc.y, inv, bb.y),
                               fmaf(acc.z, inv, bb.z), fmaf(acc.w, inv, bb.w));
        *(float4*)(g + (size_t)v * 256 + j) = o;
    } else {
        float4 r = make_float4(acc.x * inv, acc.y * inv, acc.z * inv, acc.w * inv);
        r.x += __shfl_xor(r.x, 16, 64); r.x += __shfl_xor(r.x, 32, 64);
        r.y += __shfl_xor(r.y, 16, 64); r.y += __shfl_xor(r.y, 32, 64);
        r.z += __shfl_xor(r.z, 16, 64); r.z += __shfl_xor(r.z, 32, 64);
        r.w += __shfl_xor(r.w, 16, 64); r.w += __shfl_xor(r.w, 32, 64);
        if (grp == 0) {
            float4 bb = *(const float4*)(bias + sub * 4);
            float4 o = make_float4(fmaf(r.x, 0.25f, bb.x), fmaf(r.y, 0.25f, bb.y),
                                   fmaf(r.z, 0.25f, bb.z), fmaf(r.w, 0.25f, bb.w));
            *(float4*)(g + (size_t)v * 64 + sub * 4) = o;
        }
    }
}

// ------------------------------------------------------------------
// LayerNorm(256) + residual + optional ELU; one wave per node
// ------------------------------------------------------------------
__global__ __launch_bounds__(256) void ln256_kernel(
    const float* __restrict__ gbuf, const float* __restrict__ lnw,
    const float* __restrict__ lnb, const float* __restrict__ resid,
    float* __restrict__ out, int do_elu)
{
    int v = blockIdx.x * 4 + (threadIdx.x >> 6);
    int lane = threadIdx.x & 63;
    if (v >= NN) return;
    float xv[4];
    float s = 0.f, s2 = 0.f;
#pragma unroll
    for (int k = 0; k < 4; ++k) {
        float t = gbuf[(size_t)v * 256 + k * 64 + lane];
        xv[k] = t; s += t; s2 += t * t;
    }
#pragma unroll
    for (int off = 32; off >= 1; off >>= 1) {
        s += __shfl_xor(s, off, 64);
        s2 += __shfl_xor(s2, off, 64);
    }
    float mu = s * (1.f / 256.f);
    float var = s2 * (1.f / 256.f) - mu * mu;
    float rs = rsqrtf(var + 1e-5f);
#pragma unroll
    for (int k = 0; k < 4; ++k) {
        int j = k * 64 + lane;
        float y = (xv[k] - mu) * rs * lnw[j] + lnb[j] + resid[(size_t)v * 256 + j];
        if (do_elu) y = (y > 0.f) ? y : expm1f(y);
        out[(size_t)v * 256 + j] = y;
    }
}

__global__ __launch_bounds__(256) void ln64_kernel(
    const float* __restrict__ g64, const float* __restrict__ lnw,
    const float* __restrict__ lnb, const float* __restrict__ resid64,
    float* __restrict__ out)
{
    int v = blockIdx.x * 4 + (threadIdx.x >> 6);
    int lane = threadIdx.x & 63;
    if (v >= NN) return;
    float t = g64[(size_t)v * 64 + lane];
    float s = t, s2 = t * t;
#pragma unroll
    for (int off = 32; off >= 1; off >>= 1) {
        s += __shfl_xor(s, off, 64);
        s2 += __shfl_xor(s2, off, 64);
    }
    float mu = s * (1.f / 64.f);
    float var = s2 * (1.f / 64.f) - mu * mu;
    float rs = rsqrtf(var + 1e-5f);
    out[(size_t)v * 64 + lane] =
        (t - mu) * rs * lnw[lane] + lnb[lane] + resid64[(size_t)v * 64 + lane];
}

// ------------------------------------------------------------------
extern "C" void kernel_launch(void* const* d_in, const int* in_sizes, int n_in,
                              void* d_out, int out_size, void* d_ws, size_t ws_size,
                              hipStream_t stream)
{
    const float* x    = (const float*)d_in[0];
    const int*   eidx = (const int*)d_in[1];
    const float* ea   = (const float*)d_in[2];
    const int* src = eidx;
    const int* dst = eidx + EE;

    const float *Wl[3], *bl[3], *Wr[3], *br[3], *We[3], *att[3], *temp[3],
                *bias[3], *lnw[3], *lnb[3];
    for (int i = 0; i < 3; ++i) {
        int b = 3 + i * 10;
        Wl[i]   = (const float*)d_in[b + 0];
        bl[i]   = (const float*)d_in[b + 1];
        Wr[i]   = (const float*)d_in[b + 2];
        br[i]   = (const float*)d_in[b + 3];
        We[i]   = (const float*)d_in[b + 4];
        att[i]  = (const float*)d_in[b + 5];
        temp[i] = (const float*)d_in[b + 6];
        bias[i] = (const float*)d_in[b + 7];
        lnw[i]  = (const float*)d_in[b + 8];
        lnb[i]  = (const float*)d_in[b + 9];
    }
    const float* pw0 = (const float*)d_in[33];
    const float* pb0 = (const float*)d_in[34];
    const float* pw2 = (const float*)d_in[35];
    const float* pb2 = (const float*)d_in[36];

    // workspace carve-up
    char* w = (char*)d_ws;
    float* h     = (float*)w; w += (size_t)NN * 256 * 4;
    float* g     = (float*)w; w += (size_t)NN * 256 * 4;   // also aliased as Asw
    float* xl    = (float*)w; w += (size_t)NN * 256 * 4;
    float* xr    = (float*)w; w += (size_t)NN * 256 * 4;
    float4* eap  = (float4*)w; w += (size_t)EE * 16;
    float* erec  = (float*)w; w += (size_t)EE * 4;
    int* srcp    = (int*)w;   w += (size_t)EE * 4;
    int* rowoff  = (int*)w;   w += (size_t)(NN + 16) * 4;
    int* cursor  = (int*)w;   w += (size_t)NN * 4;
    w = (char*)(((uintptr_t)w + 255) & ~(uintptr_t)255);
    _Float16* bsw[8];
    for (int i = 0; i < 8; ++i) { bsw[i] = (_Float16*)w; w += 131072; }
    _Float16* Asw = (_Float16*)g;   // 1564*KC*1024 B <= 25.7 MB < 51.2 MB

    dim3 blk(256);
    dim3 grid_e((EE + 255) / 256);
    dim3 grid_nw((NN + 3) / 4);
    const int MT = 391;   // ceil(50000/128) row-blocks; 4*MT=1564 row tiles

    auto gemmM = [&](const _Float16* B_, const float* bias_, float* C,
                     int K, int NC) {
        if (NC % 128 == 0)
            gemm_mfma<2><<<dim3(MT, NC / 128), blk, 0, stream>>>(
                Asw, B_, bias_, C, NN, K, NC);
        else
            gemm_mfma<1><<<dim3(MT, NC / 64), blk, 0, stream>>>(
                Asw, B_, bias_, C, NN, K, NC);
    };
    auto swA = [&](const float* A, int K) {
        swizzleA<<<dim3(4 * MT, (K >> 4) / 4), blk, 0, stream>>>(A, Asw, NN, K);
    };
    auto swB = [&](const float* B, _Float16* Bs, int K, int NC) {
        int pairs = (NC >> 5) * (K >> 4);
        swizzleB<<<dim3((pairs + 3) / 4), blk, 0, stream>>>(B, Bs, K, NC);
    };

    // ---- CSR by dst (shared by all 3 layers) ----
    hipMemsetAsync(cursor, 0, (size_t)NN * 4, stream);
    hipLaunchKernelGGL(hist_kernel, grid_e, blk, 0, stream, dst, cursor);
    hipLaunchKernelGGL(scan_kernel, dim3(1), dim3(1024), 0, stream, cursor, rowoff);
    hipMemsetAsync(cursor, 0, (size_t)NN * 4, stream);
    hipLaunchKernelGGL(scatter_kernel, grid_e, blk, 0, stream,
                       src, dst, ea, rowoff, cursor, srcp, eap, erec);

    // ---- weight swizzles (fp32 -> fp16 fragment order) ----
    swB(Wl[0], bsw[0], 128, 256);
    swB(Wr[0], bsw[1], 128, 256);
    swB(pw0,   bsw[2], 128, 256);
    swB(Wl[1], bsw[3], 256, 256);
    swB(Wr[1], bsw[4], 256, 256);
    swB(Wl[2], bsw[5], 256, 256);
    swB(Wr[2], bsw[6], 256, 256);
    swB(pw2,   bsw[7], 256, 64);

    // ---- Layer 0 (128 -> 256, concat, projected residual) ----
    swA(x, 128);
    gemmM(bsw[0], bl[0], xl, 128, 256);
    gemmM(bsw[1], br[0], xr, 128, 256);
    gemmM(bsw[2], pb0, h, 128, 256);        // residual projection into h
    hipLaunchKernelGGL(fused_attn_agg, grid_nw, blk, 0, stream,
                       rowoff, srcp, eap, erec, xl, xr, We[0], att[0], temp[0],
                       bias[0], g, 1);
    hipLaunchKernelGGL(ln256_kernel, grid_nw, blk, 0, stream,
                       g, lnw[0], lnb[0], h, h, 1);

    // ---- Layer 1 (256 -> 256, concat, identity residual) ----
    swA(h, 256);
    gemmM(bsw[3], bl[1], xl, 256, 256);
    gemmM(bsw[4], br[1], xr, 256, 256);
    hipLaunchKernelGGL(fused_attn_agg, grid_nw, blk, 0, stream,
                       rowoff, srcp, eap, erec, xl, xr, We[1], att[1], temp[1],
                       bias[1], g, 1);
    hipLaunchKernelGGL(ln256_kernel, grid_nw, blk, 0, stream,
                       g, lnw[1], lnb[1], h, h, 1);

    // ---- Layer 2 (256 -> 64, head-mean, projected residual, no ELU) ----
    swA(h, 256);
    gemmM(bsw[5], bl[2], xl, 256, 256);
    gemmM(bsw[6], br[2], xr, 256, 256);
    gemmM(bsw[7], pb2, h, 256, 64);         // residual projection (N x 64) into h
    hipLaunchKernelGGL(fused_attn_agg, grid_nw, blk, 0, stream,
                       rowoff, srcp, eap, erec, xl, xr, We[2], att[2], temp[2],
                       bias[2], g, 0);
    hipLaunchKernelGGL(ln64_kernel, grid_nw, blk, 0, stream,
                       g, lnw[2], lnb[2], h, (float*)d_out);
}

// Round 5
// 920.488 us; speedup vs baseline: 2.3744x; 1.2311x over previous
//
#include <hip/hip_runtime.h>
#include <math.h>

#define NN 50000
#define EE 800000
#define NB 196   // ceil(NN/256)

typedef _Float16 half8 __attribute__((ext_vector_type(8)));
typedef float floatx16 __attribute__((ext_vector_type(16)));

// ------------------------------------------------------------------
// Swizzle A (fp32 row-major M x K) into 32x32x16 MFMA A-fragment order.
// ------------------------------------------------------------------
__global__ __launch_bounds__(256) void swizzleA(
    const float* __restrict__ A, _Float16* __restrict__ Asw, int M, int K)
{
    int wave = threadIdx.x >> 6, lane = threadIdx.x & 63;
    int tile = blockIdx.x;
    int kc = blockIdx.y * 4 + wave;
    int KC = K >> 4;
    int row = tile * 32 + (lane & 31);
    int k0 = kc * 16 + (lane >> 5) * 8;
    float4 v0 = make_float4(0.f, 0.f, 0.f, 0.f);
    float4 v1 = make_float4(0.f, 0.f, 0.f, 0.f);
    if (row < M) {
        const float* p = A + (size_t)row * K + k0;
        v0 = *(const float4*)p;
        v1 = *(const float4*)(p + 4);
    }
    half8 o;
    o[0] = (_Float16)v0.x; o[1] = (_Float16)v0.y;
    o[2] = (_Float16)v0.z; o[3] = (_Float16)v0.w;
    o[4] = (_Float16)v1.x; o[5] = (_Float16)v1.y;
    o[6] = (_Float16)v1.z; o[7] = (_Float16)v1.w;
    *(half8*)(Asw + (((size_t)tile * KC + kc) * 64 + lane) * 8) = o;
}

// ------------------------------------------------------------------
// Swizzle B (fp32 K x NC) into B-fragment order.
// ------------------------------------------------------------------
__global__ __launch_bounds__(256) void swizzleB(
    const float* __restrict__ B, _Float16* __restrict__ Bsw, int K, int NC)
{
    int wave = threadIdx.x >> 6, lane = threadIdx.x & 63;
    int KC = K >> 4, NT = NC >> 5;
    int pair = blockIdx.x * 4 + wave;       // pair = nt*KC + kc
    if (pair >= NT * KC) return;
    int nt = pair / KC, kc = pair - nt * KC;
    int n = nt * 32 + (lane & 31);
    int k0 = kc * 16 + (lane >> 5) * 8;
    half8 o;
#pragma unroll
    for (int j = 0; j < 8; ++j)
        o[j] = (_Float16)B[(size_t)(k0 + j) * NC + n];
    *(half8*)(Bsw + ((size_t)pair * 64 + lane) * 8) = o;
}

// ------------------------------------------------------------------
// MFMA GEMM: C = A @ B + bias, fp16 pre-swizzled inputs, fp32 accum.
// ------------------------------------------------------------------
template<int CT>
__global__ __launch_bounds__(256) void gemm_mfma(
    const _Float16* __restrict__ Asw, const _Float16* __restrict__ Bsw,
    const float* __restrict__ bias, float* __restrict__ C,
    int M, int K, int NC)
{
    const int wave = threadIdx.x >> 6, lane = threadIdx.x & 63;
    const int KC = K >> 4;
    const int rt0 = blockIdx.x * 4 + (wave & 1) * 2;
    const int ct0 = blockIdx.y * (2 * CT) + (wave >> 1) * CT;

    const half8* Ap0 = (const half8*)Asw + (size_t)rt0 * KC * 64 + lane;
    const half8* Ap1 = Ap0 + (size_t)KC * 64;
    const half8* Bp0 = (const half8*)Bsw + (size_t)ct0 * KC * 64 + lane;
    const half8* Bp1 = Bp0 + (size_t)KC * 64;

    floatx16 acc00 = {0.f}, acc10 = {0.f}, acc01 = {0.f}, acc11 = {0.f};

    for (int kc = 0; kc < KC; ++kc) {
        half8 a0 = Ap0[(size_t)kc * 64];
        half8 a1 = Ap1[(size_t)kc * 64];
        half8 b0 = Bp0[(size_t)kc * 64];
        acc00 = __builtin_amdgcn_mfma_f32_32x32x16_f16(a0, b0, acc00, 0, 0, 0);
        acc10 = __builtin_amdgcn_mfma_f32_32x32x16_f16(a1, b0, acc10, 0, 0, 0);
        if (CT == 2) {
            half8 b1 = Bp1[(size_t)kc * 64];
            acc01 = __builtin_amdgcn_mfma_f32_32x32x16_f16(a0, b1, acc01, 0, 0, 0);
            acc11 = __builtin_amdgcn_mfma_f32_32x32x16_f16(a1, b1, acc11, 0, 0, 0);
        }
    }

    const int nlane = lane & 31, hs = lane >> 5;
#pragma unroll
    for (int c = 0; c < CT; ++c) {
        int col = (ct0 + c) * 32 + nlane;
        float bb = bias[col];
        const floatx16& a_ = (c == 0) ? acc00 : acc01;
        const floatx16& b_ = (c == 0) ? acc10 : acc11;
#pragma unroll
        for (int r = 0; r < 16; ++r) {
            int rowin = (r & 3) + 8 * (r >> 2) + 4 * hs;
            int row0 = rt0 * 32 + rowin;
            int row1 = row0 + 32;
            if (row0 < M) C[(size_t)row0 * NC + col] = a_[r] + bb;
            if (row1 < M) C[(size_t)row1 * NC + col] = b_[r] + bb;
        }
    }
}

// ------------------------------------------------------------------
// CSR build: histogram -> two-level scan -> scatter
// ------------------------------------------------------------------
__global__ __launch_bounds__(256) void hist_kernel(const int* __restrict__ dst,
                                                   int* __restrict__ deg)
{
    int e = blockIdx.x * 256 + threadIdx.x;
    if (e < EE) atomicAdd(&deg[dst[e]], 1);
}

__global__ __launch_bounds__(256) void scan_local(const int* __restrict__ deg,
                                                  int* __restrict__ rowoff,
                                                  int* __restrict__ part)
{
    __shared__ int sd[256];
    int tid = threadIdx.x;
    int i = blockIdx.x * 256 + tid;
    int v = (i < NN) ? deg[i] : 0;
    sd[tid] = v;
    __syncthreads();
    for (int off = 1; off < 256; off <<= 1) {
        int t = (tid >= off) ? sd[tid - off] : 0;
        __syncthreads();
        sd[tid] += t;
        __syncthreads();
    }
    if (i < NN) rowoff[i] = sd[tid] - v;   // local exclusive
    if (tid == 255) part[blockIdx.x] = sd[255];
}

__global__ __launch_bounds__(256) void scan_part(int* __restrict__ part,
                                                 int* __restrict__ rowoff)
{
    __shared__ int sd[256];
    int tid = threadIdx.x;
    int v = (tid < NB) ? part[tid] : 0;
    sd[tid] = v;
    __syncthreads();
    for (int off = 1; off < 256; off <<= 1) {
        int t = (tid >= off) ? sd[tid - off] : 0;
        __syncthreads();
        sd[tid] += t;
        __syncthreads();
    }
    if (tid < NB) part[tid] = sd[tid] - v;   // exclusive block offsets
    if (tid == 0) rowoff[NN] = EE;
}

__global__ __launch_bounds__(256) void scan_add(int* __restrict__ rowoff,
                                                const int* __restrict__ part)
{
    int i = blockIdx.x * 256 + threadIdx.x;
    if (i < NN) rowoff[i] += part[blockIdx.x];
}

__global__ __launch_bounds__(256) void scatter_kernel(
    const int* __restrict__ src, const int* __restrict__ dst,
    const float* __restrict__ ea, const int* __restrict__ rowoff,
    int* __restrict__ cursor, int* __restrict__ srcp,
    float4* __restrict__ eap, float* __restrict__ erec)
{
    int e = blockIdx.x * 256 + threadIdx.x;
    if (e < EE) {
        int d = dst[e];
        int pos = rowoff[d] + atomicAdd(&cursor[d], 1);
        srcp[pos] = src[e];
        const float* p = ea + (size_t)e * 5;
        eap[pos] = make_float4(p[0], p[1], p[2], p[3]);
        erec[pos] = 1.0f / fmaxf(p[3], 1e-6f);
    }
}

// ------------------------------------------------------------------
// Fused GATv2 + LayerNorm + residual (+ELU): one wave per node.
// mode 0: concat 256 -> LN256 + resid + ELU -> out row 256
// mode 1: head-mean 64 -> LN64 + resid64   -> out row 64
// Unroll x2 edge loop with merged online-softmax update.
// ------------------------------------------------------------------
__global__ __launch_bounds__(256) void fused_attn_ln(
    const int* __restrict__ rowoff, const int* __restrict__ srcp,
    const float4* __restrict__ eap, const float* __restrict__ erec,
    const float* __restrict__ xl, const float* __restrict__ xr,
    const float* __restrict__ We, const float* __restrict__ att,
    const float* __restrict__ temp, const float* __restrict__ bias,
    const float* __restrict__ lnw, const float* __restrict__ lnb,
    const float* __restrict__ resid, float* __restrict__ out, int mode)
{
    int v = __builtin_amdgcn_readfirstlane(blockIdx.x * 4 + (threadIdx.x >> 6));
    int lane = threadIdx.x & 63;
    if (v >= NN) return;
    int grp = lane >> 4;
    int sub = lane & 15;
    int j = grp * 64 + sub * 4;

    float4 w0 = *(const float4*)(We + j);
    float4 w1 = *(const float4*)(We + 256 + j);
    float4 w2 = *(const float4*)(We + 512 + j);
    float4 w3 = *(const float4*)(We + 768 + j);
    float4 w4 = *(const float4*)(We + 1024 + j);
    float4 at = *(const float4*)(att + j);
    float4 xrv = *(const float4*)(xr + (size_t)v * 256 + j);
    float tmp = temp[0];
    const float L2E = 1.44269504088896340736f;

    auto logit_pre = [&](const float4& a, float a4, const float4& xv) -> float {
        float m0 = fmaf(a.x, w0.x, fmaf(a.y, w1.x, fmaf(a.z, w2.x,
                   fmaf(a.w, w3.x, fmaf(a4, w4.x, xv.x + xrv.x)))));
        float m1 = fmaf(a.x, w0.y, fmaf(a.y, w1.y, fmaf(a.z, w2.y,
                   fmaf(a.w, w3.y, fmaf(a4, w4.y, xv.y + xrv.y)))));
        float m2 = fmaf(a.x, w0.z, fmaf(a.y, w1.z, fmaf(a.z, w2.z,
                   fmaf(a.w, w3.z, fmaf(a4, w4.z, xv.z + xrv.z)))));
        float m3 = fmaf(a.x, w0.w, fmaf(a.y, w1.w, fmaf(a.z, w2.w,
                   fmaf(a.w, w3.w, fmaf(a4, w4.w, xv.w + xrv.w)))));
        m0 = fmaxf(m0, 0.2f * m0);
        m1 = fmaxf(m1, 0.2f * m1);
        m2 = fmaxf(m2, 0.2f * m2);
        m3 = fmaxf(m3, 0.2f * m3);
        return fmaf(m3, at.w, fmaf(m2, at.z, fmaf(m1, at.y, m0 * at.x)));
    };

    float mxd = -INFINITY, dend = 0.f;
    float4 acc = make_float4(0.f, 0.f, 0.f, 0.f);

    int beg = rowoff[v], end = rowoff[v + 1];
    int i = beg;
    for (; i + 2 <= end; i += 2) {
        int s0 = srcp[i], s1 = srcp[i + 1];
        float4 a0 = eap[i], a1 = eap[i + 1];
        float a40 = tmp * erec[i], a41 = tmp * erec[i + 1];
        float4 x0 = *(const float4*)(xl + (size_t)s0 * 256 + j);
        float4 x1 = *(const float4*)(xl + (size_t)s1 * 256 + j);
        float l0 = logit_pre(a0, a40, x0);
        float l1 = logit_pre(a1, a41, x1);
        l0 += __shfl_xor(l0, 8, 64);  l1 += __shfl_xor(l1, 8, 64);
        l0 += __shfl_xor(l0, 4, 64);  l1 += __shfl_xor(l1, 4, 64);
        l0 += __shfl_xor(l0, 2, 64);  l1 += __shfl_xor(l1, 2, 64);
        l0 += __shfl_xor(l0, 1, 64);  l1 += __shfl_xor(l1, 1, 64);
        l0 *= L2E; l1 *= L2E;
        float nm = fmaxf(mxd, fmaxf(l0, l1));
        float sc = exp2f(mxd - nm);
        float e0 = exp2f(l0 - nm);
        float e1 = exp2f(l1 - nm);
        mxd = nm;
        dend = fmaf(dend, sc, e0 + e1);
        acc.x = fmaf(acc.x, sc, fmaf(x0.x, e0, x1.x * e1));
        acc.y = fmaf(acc.y, sc, fmaf(x0.y, e0, x1.y * e1));
        acc.z = fmaf(acc.z, sc, fmaf(x0.z, e0, x1.z * e1));
        acc.w = fmaf(acc.w, sc, fmaf(x0.w, e0, x1.w * e1));
    }
    if (i < end) {
        int s0 = srcp[i];
        float4 a0 = eap[i];
        float a40 = tmp * erec[i];
        float4 x0 = *(const float4*)(xl + (size_t)s0 * 256 + j);
        float l0 = logit_pre(a0, a40, x0);
        l0 += __shfl_xor(l0, 8, 64);
        l0 += __shfl_xor(l0, 4, 64);
        l0 += __shfl_xor(l0, 2, 64);
        l0 += __shfl_xor(l0, 1, 64);
        l0 *= L2E;
        float nm = fmaxf(mxd, l0);
        float sc = exp2f(mxd - nm);
        float e0 = exp2f(l0 - nm);
        mxd = nm;
        dend = fmaf(dend, sc, e0);
        acc.x = fmaf(acc.x, sc, x0.x * e0);
        acc.y = fmaf(acc.y, sc, x0.y * e0);
        acc.z = fmaf(acc.z, sc, x0.z * e0);
        acc.w = fmaf(acc.w, sc, x0.w * e0);
    }

    float inv = 1.f / (dend + 1e-16f);
    if (mode == 0) {
        float4 bb = *(const float4*)(bias + j);
        float4 o = make_float4(fmaf(acc.x, inv, bb.x), fmaf(acc.y, inv, bb.y),
                               fmaf(acc.z, inv, bb.z), fmaf(acc.w, inv, bb.w));
        float s  = o.x + o.y + o.z + o.w;
        float s2 = o.x * o.x + o.y * o.y + o.z * o.z + o.w * o.w;
#pragma unroll
        for (int off = 32; off >= 1; off >>= 1) {
            s  += __shfl_xor(s, off, 64);
            s2 += __shfl_xor(s2, off, 64);
        }
        float mu = s * (1.f / 256.f);
        float var = s2 * (1.f / 256.f) - mu * mu;
        float rs = rsqrtf(var + 1e-5f);
        float4 lw = *(const float4*)(lnw + j);
        float4 lb = *(const float4*)(lnb + j);
        float4 rr = *(const float4*)(resid + (size_t)v * 256 + j);
        float4 y;
        y.x = fmaf((o.x - mu) * rs, lw.x, lb.x) + rr.x;
        y.y = fmaf((o.y - mu) * rs, lw.y, lb.y) + rr.y;
        y.z = fmaf((o.z - mu) * rs, lw.z, lb.z) + rr.z;
        y.w = fmaf((o.w - mu) * rs, lw.w, lb.w) + rr.w;
        y.x = (y.x > 0.f) ? y.x : expm1f(y.x);
        y.y = (y.y > 0.f) ? y.y : expm1f(y.y);
        y.z = (y.z > 0.f) ? y.z : expm1f(y.z);
        y.w = (y.w > 0.f) ? y.w : expm1f(y.w);
        *(float4*)(out + (size_t)v * 256 + j) = y;
    } else {
        float4 r = make_float4(acc.x * inv, acc.y * inv, acc.z * inv, acc.w * inv);
        r.x += __shfl_xor(r.x, 16, 64); r.x += __shfl_xor(r.x, 32, 64);
        r.y += __shfl_xor(r.y, 16, 64); r.y += __shfl_xor(r.y, 32, 64);
        r.z += __shfl_xor(r.z, 16, 64); r.z += __shfl_xor(r.z, 32, 64);
        r.w += __shfl_xor(r.w, 16, 64); r.w += __shfl_xor(r.w, 32, 64);
        float4 bb = *(const float4*)(bias + sub * 4);
        float4 o = make_float4(fmaf(r.x, 0.25f, bb.x), fmaf(r.y, 0.25f, bb.y),
                               fmaf(r.z, 0.25f, bb.z), fmaf(r.w, 0.25f, bb.w));
        float s  = o.x + o.y + o.z + o.w;
        float s2 = o.x * o.x + o.y * o.y + o.z * o.z + o.w * o.w;
#pragma unroll
        for (int off = 8; off >= 1; off >>= 1) {   // within 16-lane group
            s  += __shfl_xor(s, off, 64);
            s2 += __shfl_xor(s2, off, 64);
        }
        float mu = s * (1.f / 64.f);
        float var = s2 * (1.f / 64.f) - mu * mu;
        float rs = rsqrtf(var + 1e-5f);
        float4 lw = *(const float4*)(lnw + sub * 4);
        float4 lb = *(const float4*)(lnb + sub * 4);
        float4 rr = *(const float4*)(resid + (size_t)v * 64 + sub * 4);
        float4 y;
        y.x = fmaf((o.x - mu) * rs, lw.x, lb.x) + rr.x;
        y.y = fmaf((o.y - mu) * rs, lw.y, lb.y) + rr.y;
        y.z = fmaf((o.z - mu) * rs, lw.z, lb.z) + rr.z;
        y.w = fmaf((o.w - mu) * rs, lw.w, lb.w) + rr.w;
        if (grp == 0)
            *(float4*)(out + (size_t)v * 64 + sub * 4) = y;
    }
}

// ------------------------------------------------------------------
extern "C" void kernel_launch(void* const* d_in, const int* in_sizes, int n_in,
                              void* d_out, int out_size, void* d_ws, size_t ws_size,
                              hipStream_t stream)
{
    const float* x    = (const float*)d_in[0];
    const int*   eidx = (const int*)d_in[1];
    const float* ea   = (const float*)d_in[2];
    const int* src = eidx;
    const int* dst = eidx + EE;

    const float *Wl[3], *bl[3], *Wr[3], *br[3], *We[3], *att[3], *temp[3],
                *bias[3], *lnw[3], *lnb[3];
    for (int i = 0; i < 3; ++i) {
        int b = 3 + i * 10;
        Wl[i]   = (const float*)d_in[b + 0];
        bl[i]   = (const float*)d_in[b + 1];
        Wr[i]   = (const float*)d_in[b + 2];
        br[i]   = (const float*)d_in[b + 3];
        We[i]   = (const float*)d_in[b + 4];
        att[i]  = (const float*)d_in[b + 5];
        temp[i] = (const float*)d_in[b + 6];
        bias[i] = (const float*)d_in[b + 7];
        lnw[i]  = (const float*)d_in[b + 8];
        lnb[i]  = (const float*)d_in[b + 9];
    }
    const float* pw0 = (const float*)d_in[33];
    const float* pb0 = (const float*)d_in[34];
    const float* pw2 = (const float*)d_in[35];
    const float* pb2 = (const float*)d_in[36];

    // workspace carve-up
    char* w = (char*)d_ws;
    float* h     = (float*)w; w += (size_t)NN * 256 * 4;
    char*  gbase = w;         w += (size_t)NN * 256 * 4;   // Asw + r64 region
    float* xl    = (float*)w; w += (size_t)NN * 256 * 4;
    float* xr    = (float*)w; w += (size_t)NN * 256 * 4;
    float4* eap  = (float4*)w; w += (size_t)EE * 16;
    float* erec  = (float*)w; w += (size_t)EE * 4;
    int* srcp    = (int*)w;   w += (size_t)EE * 4;
    int* rowoff  = (int*)w;   w += (size_t)(NN + 16) * 4;
    int* cursor  = (int*)w;   w += (size_t)NN * 4;
    int* part    = (int*)w;   w += 1024;
    w = (char*)(((uintptr_t)w + 255) & ~(uintptr_t)255);
    _Float16* bsw[8];
    for (int i = 0; i < 8; ++i) { bsw[i] = (_Float16*)w; w += 131072; }
    _Float16* Asw = (_Float16*)gbase;           // <= 25.7 MB
    float* r64 = (float*)(gbase + (size_t)32 * 1024 * 1024);   // 12.8 MB

    dim3 blk(256);
    dim3 grid_e((EE + 255) / 256);
    dim3 grid_nw((NN + 3) / 4);
    dim3 grid_nb(NB);
    const int MT = 391;   // ceil(50000/128)

    auto gemmM = [&](const _Float16* B_, const float* bias_, float* C,
                     int K, int NC) {
        if (NC % 128 == 0)
            gemm_mfma<2><<<dim3(MT, NC / 128), blk, 0, stream>>>(
                Asw, B_, bias_, C, NN, K, NC);
        else
            gemm_mfma<1><<<dim3(MT, NC / 64), blk, 0, stream>>>(
                Asw, B_, bias_, C, NN, K, NC);
    };
    auto swA = [&](const float* A, int K) {
        swizzleA<<<dim3(4 * MT, (K >> 4) / 4), blk, 0, stream>>>(A, Asw, NN, K);
    };
    auto swB = [&](const float* B, _Float16* Bs, int K, int NC) {
        int pairs = (NC >> 5) * (K >> 4);
        swizzleB<<<dim3((pairs + 3) / 4), blk, 0, stream>>>(B, Bs, K, NC);
    };
    auto attn = [&](const float* xl_, const float* xr_, int L,
                    const float* resid, float* outp, int mode) {
        fused_attn_ln<<<grid_nw, blk, 0, stream>>>(
            rowoff, srcp, eap, erec, xl_, xr_, We[L], att[L], temp[L],
            bias[L], lnw[L], lnb[L], resid, outp, mode);
    };

    // ---- CSR by dst (shared by all 3 layers) ----
    hipMemsetAsync(cursor, 0, (size_t)NN * 4, stream);
    hipLaunchKernelGGL(hist_kernel, grid_e, blk, 0, stream, dst, cursor);
    hipLaunchKernelGGL(scan_local, grid_nb, blk, 0, stream, cursor, rowoff, part);
    hipLaunchKernelGGL(scan_part, dim3(1), blk, 0, stream, part, rowoff);
    hipLaunchKernelGGL(scan_add, grid_nb, blk, 0, stream, rowoff, part);
    hipMemsetAsync(cursor, 0, (size_t)NN * 4, stream);
    hipLaunchKernelGGL(scatter_kernel, grid_e, blk, 0, stream,
                       src, dst, ea, rowoff, cursor, srcp, eap, erec);

    // ---- weight swizzles (fp32 -> fp16 fragment order) ----
    swB(Wl[0], bsw[0], 128, 256);
    swB(Wr[0], bsw[1], 128, 256);
    swB(pw0,   bsw[2], 128, 256);
    swB(Wl[1], bsw[3], 256, 256);
    swB(Wr[1], bsw[4], 256, 256);
    swB(Wl[2], bsw[5], 256, 256);
    swB(Wr[2], bsw[6], 256, 256);
    swB(pw2,   bsw[7], 256, 64);

    // ---- Layer 0 (128 -> 256, concat, projected residual) ----
    swA(x, 128);
    gemmM(bsw[0], bl[0], xl, 128, 256);
    gemmM(bsw[1], br[0], xr, 128, 256);
    gemmM(bsw[2], pb0, h, 128, 256);         // residual projection into h
    attn(xl, xr, 0, h, h, 0);                // GAT + LN256 + resid + ELU -> h

    // ---- Layer 1 (256 -> 256, concat, identity residual) ----
    swA(h, 256);
    gemmM(bsw[3], bl[1], xl, 256, 256);
    gemmM(bsw[4], br[1], xr, 256, 256);
    attn(xl, xr, 1, h, h, 0);                // resid = h, out = h (row-local)

    // ---- Layer 2 (256 -> 64, head-mean, projected residual, no ELU) ----
    swA(h, 256);
    gemmM(bsw[5], bl[2], xl, 256, 256);
    gemmM(bsw[6], br[2], xr, 256, 256);
    gemmM(bsw[7], pb2, r64, 256, 64);        // residual projection (N x 64)
    attn(xl, xr, 2, r64, (float*)d_out, 1);  // GAT + LN64 + resid -> out
}

// Round 6
// 767.957 us; speedup vs baseline: 2.8459x; 1.1986x over previous
//
#include <hip/hip_runtime.h>
#include <math.h>

#define NN 50000
#define EE 800000
#define NB 196   // ceil(NN/256)

typedef _Float16 half8 __attribute__((ext_vector_type(8)));
typedef _Float16 hv4  __attribute__((ext_vector_type(4)));
typedef float floatx16 __attribute__((ext_vector_type(16)));
typedef float fv4 __attribute__((ext_vector_type(4)));

// DPP row_ror all-reduce within 16-lane rows: rotations by 1,2,4,8.
template<int CTRL>
__device__ __forceinline__ float dppadd(float x) {
    int t = __builtin_amdgcn_update_dpp(0, __float_as_int(x), CTRL, 0xf, 0xf, false);
    return x + __int_as_float(t);
}
__device__ __forceinline__ float red16(float x) {
    x = dppadd<0x121>(x);   // row_ror:1
    x = dppadd<0x122>(x);   // row_ror:2
    x = dppadd<0x124>(x);   // row_ror:4
    x = dppadd<0x128>(x);   // row_ror:8
    return x;
}

// ------------------------------------------------------------------
// Swizzle A (fp32 row-major M x K) into 32x32x16 MFMA A-fragment order.
// ------------------------------------------------------------------
__global__ __launch_bounds__(256) void swizzleA(
    const float* __restrict__ A, _Float16* __restrict__ Asw, int M, int K)
{
    int wave = threadIdx.x >> 6, lane = threadIdx.x & 63;
    int tile = blockIdx.x;
    int kc = blockIdx.y * 4 + wave;
    int KC = K >> 4;
    int row = tile * 32 + (lane & 31);
    int k0 = kc * 16 + (lane >> 5) * 8;
    float4 v0 = make_float4(0.f, 0.f, 0.f, 0.f);
    float4 v1 = make_float4(0.f, 0.f, 0.f, 0.f);
    if (row < M) {
        const float* p = A + (size_t)row * K + k0;
        v0 = *(const float4*)p;
        v1 = *(const float4*)(p + 4);
    }
    half8 o;
    o[0] = (_Float16)v0.x; o[1] = (_Float16)v0.y;
    o[2] = (_Float16)v0.z; o[3] = (_Float16)v0.w;
    o[4] = (_Float16)v1.x; o[5] = (_Float16)v1.y;
    o[6] = (_Float16)v1.z; o[7] = (_Float16)v1.w;
    *(half8*)(Asw + (((size_t)tile * KC + kc) * 64 + lane) * 8) = o;
}

// ------------------------------------------------------------------
// Swizzle B (fp32 K x NC) into B-fragment order at given dest base.
// ------------------------------------------------------------------
__global__ __launch_bounds__(256) void swizzleB(
    const float* __restrict__ B, _Float16* __restrict__ Bsw, int K, int NC)
{
    int wave = threadIdx.x >> 6, lane = threadIdx.x & 63;
    int KC = K >> 4, NT = NC >> 5;
    int pair = blockIdx.x * 4 + wave;       // pair = nt*KC + kc
    if (pair >= NT * KC) return;
    int nt = pair / KC, kc = pair - nt * KC;
    int n = nt * 32 + (lane & 31);
    int k0 = kc * 16 + (lane >> 5) * 8;
    half8 o;
#pragma unroll
    for (int j = 0; j < 8; ++j)
        o[j] = (_Float16)B[(size_t)(k0 + j) * NC + n];
    *(half8*)(Bsw + ((size_t)pair * 64 + lane) * 8) = o;
}

// concat up to 3 fp32 vectors
__global__ __launch_bounds__(256) void cat3(
    const float* __restrict__ b0, int n0, const float* __restrict__ b1, int n1,
    const float* __restrict__ b2, int n2, float* __restrict__ out)
{
    int i = blockIdx.x * 256 + threadIdx.x;
    if (i < n0) out[i] = b0[i];
    else if (i < n0 + n1) out[i] = b1[i - n0];
    else if (i < n0 + n1 + n2) out[i] = b2[i - n0 - n1];
}

// ------------------------------------------------------------------
// MFMA GEMM: C = A @ B + bias, fp16 pre-swizzled inputs, fp32 accum,
// output type OT (float or _Float16).
// ------------------------------------------------------------------
template<int CT, typename OT>
__global__ __launch_bounds__(256) void gemm_mfma(
    const _Float16* __restrict__ Asw, const _Float16* __restrict__ Bsw,
    const float* __restrict__ bias, OT* __restrict__ C,
    int M, int K, int NC)
{
    const int wave = threadIdx.x >> 6, lane = threadIdx.x & 63;
    const int KC = K >> 4;
    const int rt0 = blockIdx.x * 4 + (wave & 1) * 2;
    const int ct0 = blockIdx.y * (2 * CT) + (wave >> 1) * CT;

    const half8* Ap0 = (const half8*)Asw + (size_t)rt0 * KC * 64 + lane;
    const half8* Ap1 = Ap0 + (size_t)KC * 64;
    const half8* Bp0 = (const half8*)Bsw + (size_t)ct0 * KC * 64 + lane;
    const half8* Bp1 = Bp0 + (size_t)KC * 64;

    floatx16 acc00 = {0.f}, acc10 = {0.f}, acc01 = {0.f}, acc11 = {0.f};

    for (int kc = 0; kc < KC; ++kc) {
        half8 a0 = Ap0[(size_t)kc * 64];
        half8 a1 = Ap1[(size_t)kc * 64];
        half8 b0 = Bp0[(size_t)kc * 64];
        acc00 = __builtin_amdgcn_mfma_f32_32x32x16_f16(a0, b0, acc00, 0, 0, 0);
        acc10 = __builtin_amdgcn_mfma_f32_32x32x16_f16(a1, b0, acc10, 0, 0, 0);
        if (CT == 2) {
            half8 b1 = Bp1[(size_t)kc * 64];
            acc01 = __builtin_amdgcn_mfma_f32_32x32x16_f16(a0, b1, acc01, 0, 0, 0);
            acc11 = __builtin_amdgcn_mfma_f32_32x32x16_f16(a1, b1, acc11, 0, 0, 0);
        }
    }

    const int nlane = lane & 31, hs = lane >> 5;
#pragma unroll
    for (int c = 0; c < CT; ++c) {
        int col = (ct0 + c) * 32 + nlane;
        float bb = bias[col];
        const floatx16& a_ = (c == 0) ? acc00 : acc01;
        const floatx16& b_ = (c == 0) ? acc10 : acc11;
#pragma unroll
        for (int r = 0; r < 16; ++r) {
            int rowin = (r & 3) + 8 * (r >> 2) + 4 * hs;
            int row0 = rt0 * 32 + rowin;
            int row1 = row0 + 32;
            if (row0 < M) C[(size_t)row0 * NC + col] = (OT)(a_[r] + bb);
            if (row1 < M) C[(size_t)row1 * NC + col] = (OT)(b_[r] + bb);
        }
    }
}

// ------------------------------------------------------------------
// CSR build: histogram -> two-level scan -> scatter
// ------------------------------------------------------------------
__global__ __launch_bounds__(256) void hist_kernel(const int* __restrict__ dst,
                                                   int* __restrict__ deg)
{
    int e = blockIdx.x * 256 + threadIdx.x;
    if (e < EE) atomicAdd(&deg[dst[e]], 1);
}

__global__ __launch_bounds__(256) void scan_local(const int* __restrict__ deg,
                                                  int* __restrict__ rowoff,
                                                  int* __restrict__ part)
{
    __shared__ int sd[256];
    int tid = threadIdx.x;
    int i = blockIdx.x * 256 + tid;
    int v = (i < NN) ? deg[i] : 0;
    sd[tid] = v;
    __syncthreads();
    for (int off = 1; off < 256; off <<= 1) {
        int t = (tid >= off) ? sd[tid - off] : 0;
        __syncthreads();
        sd[tid] += t;
        __syncthreads();
    }
    if (i < NN) rowoff[i] = sd[tid] - v;
    if (tid == 255) part[blockIdx.x] = sd[255];
}

__global__ __launch_bounds__(256) void scan_part(int* __restrict__ part,
                                                 int* __restrict__ rowoff)
{
    __shared__ int sd[256];
    int tid = threadIdx.x;
    int v = (tid < NB) ? part[tid] : 0;
    sd[tid] = v;
    __syncthreads();
    for (int off = 1; off < 256; off <<= 1) {
        int t = (tid >= off) ? sd[tid - off] : 0;
        __syncthreads();
        sd[tid] += t;
        __syncthreads();
    }
    if (tid < NB) part[tid] = sd[tid] - v;
    if (tid == 0) rowoff[NN] = EE;
}

__global__ __launch_bounds__(256) void scan_add(int* __restrict__ rowoff,
                                                const int* __restrict__ part)
{
    int i = blockIdx.x * 256 + threadIdx.x;
    if (i < NN) rowoff[i] += part[blockIdx.x];
}

__global__ __launch_bounds__(256) void scatter_kernel(
    const int* __restrict__ src, const int* __restrict__ dst,
    const float* __restrict__ ea, const int* __restrict__ rowoff,
    int* __restrict__ cursor, int* __restrict__ srcp,
    float4* __restrict__ eap, float* __restrict__ erec)
{
    int e = blockIdx.x * 256 + threadIdx.x;
    if (e < EE) {
        int d = dst[e];
        int pos = rowoff[d] + atomicAdd(&cursor[d], 1);
        srcp[pos] = src[e];
        const float* p = ea + (size_t)e * 5;
        eap[pos] = make_float4(p[0], p[1], p[2], p[3]);
        erec[pos] = 1.0f / fmaxf(p[3], 1e-6f);
    }
}

// ------------------------------------------------------------------
// Fused GATv2 + LayerNorm + residual (+ELU): one wave per node.
// fp16 xl/xr gathers, packed fp32 vector math, DPP row-reductions.
// mode 0: concat 256, fp16 resid (row slice), ELU
// mode 1: concat 256, fp32 resid (stride 256), ELU
// mode 2: head-mean 64, fp32 resid (stride 64), no ELU
// ------------------------------------------------------------------
__global__ __launch_bounds__(256) void fused_attn_ln(
    const int* __restrict__ rowoff, const int* __restrict__ srcp,
    const float4* __restrict__ eap, const float* __restrict__ erec,
    const _Float16* __restrict__ xlp, int rstride,
    const float* __restrict__ We, const float* __restrict__ att,
    const float* __restrict__ temp, const float* __restrict__ bias,
    const float* __restrict__ lnw, const float* __restrict__ lnb,
    const _Float16* __restrict__ residH, const float* __restrict__ residF,
    float* __restrict__ out, int mode)
{
    int v = __builtin_amdgcn_readfirstlane(blockIdx.x * 4 + (threadIdx.x >> 6));
    int lane = threadIdx.x & 63;
    if (v >= NN) return;
    int grp = lane >> 4;
    int sub = lane & 15;
    int j = grp * 64 + sub * 4;

    fv4 ww0 = *(const fv4*)(We + j);
    fv4 ww1 = *(const fv4*)(We + 256 + j);
    fv4 ww2 = *(const fv4*)(We + 512 + j);
    fv4 ww3 = *(const fv4*)(We + 768 + j);
    fv4 ww4 = *(const fv4*)(We + 1024 + j);
    fv4 atv = *(const fv4*)(att + j);
    fv4 xrv = __builtin_convertvector(
        *(const hv4*)(xlp + (size_t)v * rstride + 256 + j), fv4);
    float tmp = temp[0];
    const float L2E = 1.44269504088896340736f;

    float mxd = -INFINITY, dend = 0.f;
    fv4 acc = {0.f, 0.f, 0.f, 0.f};

    int beg = rowoff[v], end = rowoff[v + 1];
    int i = beg;
    for (; i + 2 <= end; i += 2) {
        int s0 = srcp[i], s1 = srcp[i + 1];
        float4 a0 = eap[i], a1 = eap[i + 1];
        float q0 = tmp * erec[i], q1 = tmp * erec[i + 1];
        fv4 x0 = __builtin_convertvector(
            *(const hv4*)(xlp + (size_t)s0 * rstride + j), fv4);
        fv4 x1 = __builtin_convertvector(
            *(const hv4*)(xlp + (size_t)s1 * rstride + j), fv4);
        fv4 m0 = x0 + xrv;
        m0 = m0 + a0.x * ww0; m0 = m0 + a0.y * ww1; m0 = m0 + a0.z * ww2;
        m0 = m0 + a0.w * ww3; m0 = m0 + q0 * ww4;
        fv4 m1 = x1 + xrv;
        m1 = m1 + a1.x * ww0; m1 = m1 + a1.y * ww1; m1 = m1 + a1.z * ww2;
        m1 = m1 + a1.w * ww3; m1 = m1 + q1 * ww4;
        m0 = __builtin_elementwise_max(m0, m0 * 0.2f);
        m1 = __builtin_elementwise_max(m1, m1 * 0.2f);
        fv4 p0 = m0 * atv, p1 = m1 * atv;
        float l0 = (p0[0] + p0[1]) + (p0[2] + p0[3]);
        float l1 = (p1[0] + p1[1]) + (p1[2] + p1[3]);
        l0 = red16(l0) * L2E;
        l1 = red16(l1) * L2E;
        float nm = fmaxf(mxd, fmaxf(l0, l1));
        float sc = exp2f(mxd - nm);
        float e0 = exp2f(l0 - nm);
        float e1 = exp2f(l1 - nm);
        mxd = nm;
        dend = dend * sc + (e0 + e1);
        acc = acc * sc + (x0 * e0 + x1 * e1);
    }
    if (i < end) {
        int s0 = srcp[i];
        float4 a0 = eap[i];
        float q0 = tmp * erec[i];
        fv4 x0 = __builtin_convertvector(
            *(const hv4*)(xlp + (size_t)s0 * rstride + j), fv4);
        fv4 m0 = x0 + xrv;
        m0 = m0 + a0.x * ww0; m0 = m0 + a0.y * ww1; m0 = m0 + a0.z * ww2;
        m0 = m0 + a0.w * ww3; m0 = m0 + q0 * ww4;
        m0 = __builtin_elementwise_max(m0, m0 * 0.2f);
        fv4 p0 = m0 * atv;
        float l0 = (p0[0] + p0[1]) + (p0[2] + p0[3]);
        l0 = red16(l0) * L2E;
        float nm = fmaxf(mxd, l0);
        float sc = exp2f(mxd - nm);
        float e0 = exp2f(l0 - nm);
        mxd = nm;
        dend = dend * sc + e0;
        acc = acc * sc + x0 * e0;
    }

    float inv = 1.f / (dend + 1e-16f);
    if (mode <= 1) {
        fv4 bb = *(const fv4*)(bias + j);
        fv4 o = acc * inv + bb;
        float s  = (o[0] + o[1]) + (o[2] + o[3]);
        fv4 oq = o * o;
        float s2 = (oq[0] + oq[1]) + (oq[2] + oq[3]);
        s = red16(s);   s += __shfl_xor(s, 16, 64);  s += __shfl_xor(s, 32, 64);
        s2 = red16(s2); s2 += __shfl_xor(s2, 16, 64); s2 += __shfl_xor(s2, 32, 64);
        float mu = s * (1.f / 256.f);
        float var = s2 * (1.f / 256.f) - mu * mu;
        float rs = rsqrtf(var + 1e-5f);
        fv4 lw = *(const fv4*)(lnw + j);
        fv4 lb = *(const fv4*)(lnb + j);
        fv4 rr;
        if (mode == 0)
            rr = __builtin_convertvector(
                *(const hv4*)(residH + (size_t)v * rstride + j), fv4);
        else
            rr = *(const fv4*)(residF + (size_t)v * 256 + j);
        fv4 y = (o - mu) * rs * lw + lb + rr;
        y[0] = (y[0] > 0.f) ? y[0] : expm1f(y[0]);
        y[1] = (y[1] > 0.f) ? y[1] : expm1f(y[1]);
        y[2] = (y[2] > 0.f) ? y[2] : expm1f(y[2]);
        y[3] = (y[3] > 0.f) ? y[3] : expm1f(y[3]);
        *(fv4*)(out + (size_t)v * 256 + j) = y;
    } else {
        fv4 r = acc * inv;
        r[0] += __shfl_xor(r[0], 16, 64); r[0] += __shfl_xor(r[0], 32, 64);
        r[1] += __shfl_xor(r[1], 16, 64); r[1] += __shfl_xor(r[1], 32, 64);
        r[2] += __shfl_xor(r[2], 16, 64); r[2] += __shfl_xor(r[2], 32, 64);
        r[3] += __shfl_xor(r[3], 16, 64); r[3] += __shfl_xor(r[3], 32, 64);
        fv4 bb = *(const fv4*)(bias + sub * 4);
        fv4 o = r * 0.25f + bb;
        float s  = (o[0] + o[1]) + (o[2] + o[3]);
        fv4 oq = o * o;
        float s2 = (oq[0] + oq[1]) + (oq[2] + oq[3]);
        s = red16(s);
        s2 = red16(s2);
        float mu = s * (1.f / 64.f);
        float var = s2 * (1.f / 64.f) - mu * mu;
        float rs = rsqrtf(var + 1e-5f);
        fv4 lw = *(const fv4*)(lnw + sub * 4);
        fv4 lb = *(const fv4*)(lnb + sub * 4);
        fv4 rr = *(const fv4*)(residF + (size_t)v * 64 + sub * 4);
        fv4 y = (o - mu) * rs * lw + lb + rr;
        if (grp == 0)
            *(fv4*)(out + (size_t)v * 64 + sub * 4) = y;
    }
}

// ------------------------------------------------------------------
extern "C" void kernel_launch(void* const* d_in, const int* in_sizes, int n_in,
                              void* d_out, int out_size, void* d_ws, size_t ws_size,
                              hipStream_t stream)
{
    const float* x    = (const float*)d_in[0];
    const int*   eidx = (const int*)d_in[1];
    const float* ea   = (const float*)d_in[2];
    const int* src = eidx;
    const int* dst = eidx + EE;

    const float *Wl[3], *bl[3], *Wr[3], *br[3], *We[3], *att[3], *temp[3],
                *bias[3], *lnw[3], *lnb[3];
    for (int i = 0; i < 3; ++i) {
        int b = 3 + i * 10;
        Wl[i]   = (const float*)d_in[b + 0];
        bl[i]   = (const float*)d_in[b + 1];
        Wr[i]   = (const float*)d_in[b + 2];
        br[i]   = (const float*)d_in[b + 3];
        We[i]   = (const float*)d_in[b + 4];
        att[i]  = (const float*)d_in[b + 5];
        temp[i] = (const float*)d_in[b + 6];
        bias[i] = (const float*)d_in[b + 7];
        lnw[i]  = (const float*)d_in[b + 8];
        lnb[i]  = (const float*)d_in[b + 9];
    }
    const float* pw0 = (const float*)d_in[33];
    const float* pb0 = (const float*)d_in[34];
    const float* pw2 = (const float*)d_in[35];
    const float* pb2 = (const float*)d_in[36];

    // workspace carve-up
    char* w = (char*)d_ws;
    float* h     = (float*)w; w += (size_t)NN * 256 * 4;          // 51.2 MB
    char*  gbase = w;         w += (size_t)NN * 256 * 4;          // Asw + r64
    _Float16* xlr = (_Float16*)w; w += (size_t)NN * 768 * 2;      // 76.8 MB
    float4* eap  = (float4*)w; w += (size_t)EE * 16;
    float* erec  = (float*)w; w += (size_t)EE * 4;
    int* srcp    = (int*)w;   w += (size_t)EE * 4;
    int* rowoff  = (int*)w;   w += (size_t)(NN + 16) * 4;
    int* cursor  = (int*)w;   w += (size_t)NN * 4;
    int* part    = (int*)w;   w += 1024;
    w = (char*)(((uintptr_t)w + 255) & ~(uintptr_t)255);
    _Float16* catB0 = (_Float16*)w; w += 196608;   // 24 nt x 8 kc x 512 h
    _Float16* catB1 = (_Float16*)w; w += 262144;   // 16 nt x 16 kc
    _Float16* catB2 = (_Float16*)w; w += 262144;
    _Float16* B3    = (_Float16*)w; w += 32768;    // pw2: 2 nt x 16 kc
    float* cb0 = (float*)w; w += 768 * 4;
    float* cb1 = (float*)w; w += 512 * 4;
    float* cb2 = (float*)w; w += 512 * 4;
    _Float16* Asw = (_Float16*)gbase;                        // <= 25.7 MB
    float* r64 = (float*)(gbase + (size_t)32 * 1024 * 1024); // 12.8 MB

    dim3 blk(256);
    dim3 grid_e((EE + 255) / 256);
    dim3 grid_nw((NN + 3) / 4);
    dim3 grid_nb(NB);
    const int MT = 391;   // ceil(50000/128)

    auto swA = [&](const float* A, int K) {
        swizzleA<<<dim3(4 * MT, (K >> 4) / 4), blk, 0, stream>>>(A, Asw, NN, K);
    };
    auto swB = [&](const float* B, _Float16* dest, int K, int NC) {
        int pairs = (NC >> 5) * (K >> 4);
        swizzleB<<<dim3((pairs + 3) / 4), blk, 0, stream>>>(B, dest, K, NC);
    };
    auto attn = [&](int L, int rstride, const _Float16* residH,
                    const float* residF, float* outp, int mode) {
        fused_attn_ln<<<grid_nw, blk, 0, stream>>>(
            rowoff, srcp, eap, erec, xlr, rstride, We[L], att[L], temp[L],
            bias[L], lnw[L], lnb[L], residH, residF, outp, mode);
    };

    // ---- CSR by dst (shared by all 3 layers) ----
    hipMemsetAsync(cursor, 0, (size_t)NN * 4, stream);
    hipLaunchKernelGGL(hist_kernel, grid_e, blk, 0, stream, dst, cursor);
    hipLaunchKernelGGL(scan_local, grid_nb, blk, 0, stream, cursor, rowoff, part);
    hipLaunchKernelGGL(scan_part, dim3(1), blk, 0, stream, part, rowoff);
    hipLaunchKernelGGL(scan_add, grid_nb, blk, 0, stream, rowoff, part);
    hipMemsetAsync(cursor, 0, (size_t)NN * 4, stream);
    hipLaunchKernelGGL(scatter_kernel, grid_e, blk, 0, stream,
                       src, dst, ea, rowoff, cursor, srcp, eap, erec);

    // ---- weight swizzles into concatenated B buffers ----
    // K=128: per-ntile = 8 kc * 512 halves = 4096
    swB(Wl[0], catB0,              128, 256);
    swB(Wr[0], catB0 + 8 * 4096,   128, 256);
    swB(pw0,   catB0 + 16 * 4096,  128, 256);
    // K=256: per-ntile = 16 kc * 512 = 8192
    swB(Wl[1], catB1,              256, 256);
    swB(Wr[1], catB1 + 8 * 8192,   256, 256);
    swB(Wl[2], catB2,              256, 256);
    swB(Wr[2], catB2 + 8 * 8192,   256, 256);
    swB(pw2,   B3,                 256, 64);
    // concatenated biases
    cat3<<<dim3(3), blk, 0, stream>>>(bl[0], 256, br[0], 256, pb0, 256, cb0);
    cat3<<<dim3(2), blk, 0, stream>>>(bl[1], 256, br[1], 256, nullptr, 0, cb1);
    cat3<<<dim3(2), blk, 0, stream>>>(bl[2], 256, br[2], 256, nullptr, 0, cb2);

    // ---- Layer 0: one GEMM -> [xl|xr|res] fp16 rows of 768 ----
    swA(x, 128);
    gemm_mfma<2, _Float16><<<dim3(MT, 6), blk, 0, stream>>>(
        Asw, catB0, cb0, xlr, NN, 128, 768);
    attn(0, 768, xlr + 512, nullptr, h, 0);     // GAT+LN256+resid(fp16)+ELU -> h

    // ---- Layer 1: one GEMM -> [xl|xr] fp16 rows of 512, resid = h ----
    swA(h, 256);
    gemm_mfma<2, _Float16><<<dim3(MT, 4), blk, 0, stream>>>(
        Asw, catB1, cb1, xlr, NN, 256, 512);
    attn(1, 512, nullptr, h, h, 1);             // resid = h (fp32), out = h

    // ---- Layer 2: [xl|xr] fp16 + fp32 r64 projection ----
    swA(h, 256);
    gemm_mfma<2, _Float16><<<dim3(MT, 4), blk, 0, stream>>>(
        Asw, catB2, cb2, xlr, NN, 256, 512);
    gemm_mfma<1, float><<<dim3(MT, 1), blk, 0, stream>>>(
        Asw, B3, pb2, r64, NN, 256, 64);
    attn(2, 512, nullptr, r64, (float*)d_out, 2);  // GAT+LN64+resid -> out
}

// Round 7
// 707.380 us; speedup vs baseline: 3.0897x; 1.0856x over previous
//
#include <hip/hip_runtime.h>
#include <math.h>

#define NN 50000
#define EE 800000
#define NB 196   // ceil(NN/256)

typedef _Float16 half8 __attribute__((ext_vector_type(8)));
typedef _Float16 hv4  __attribute__((ext_vector_type(4)));
typedef float floatx16 __attribute__((ext_vector_type(16)));
typedef float fv4 __attribute__((ext_vector_type(4)));

__device__ __forceinline__ float fexp2(float x) { return __builtin_amdgcn_exp2f(x); }

// DPP row_ror all-reduce within 16-lane rows: rotations by 1,2,4,8.
template<int CTRL>
__device__ __forceinline__ float dppadd(float x) {
    int t = __builtin_amdgcn_update_dpp(0, __float_as_int(x), CTRL, 0xf, 0xf, false);
    return x + __int_as_float(t);
}
__device__ __forceinline__ float red16(float x) {
    x = dppadd<0x121>(x);   // row_ror:1
    x = dppadd<0x122>(x);   // row_ror:2
    x = dppadd<0x124>(x);   // row_ror:4
    x = dppadd<0x128>(x);   // row_ror:8
    return x;
}

// ------------------------------------------------------------------
// Swizzle A (fp32 row-major M x K) into 32x32x16 MFMA A-fragment order.
// Used only for the input x (K=128); later layers fuse this into attn.
// ------------------------------------------------------------------
__global__ __launch_bounds__(256) void swizzleA(
    const float* __restrict__ A, _Float16* __restrict__ Asw, int M, int K)
{
    int wave = threadIdx.x >> 6, lane = threadIdx.x & 63;
    int tile = blockIdx.x;
    int kc = blockIdx.y * 4 + wave;
    int KC = K >> 4;
    int row = tile * 32 + (lane & 31);
    int k0 = kc * 16 + (lane >> 5) * 8;
    float4 v0 = make_float4(0.f, 0.f, 0.f, 0.f);
    float4 v1 = make_float4(0.f, 0.f, 0.f, 0.f);
    if (row < M) {
        const float* p = A + (size_t)row * K + k0;
        v0 = *(const float4*)p;
        v1 = *(const float4*)(p + 4);
    }
    half8 o;
    o[0] = (_Float16)v0.x; o[1] = (_Float16)v0.y;
    o[2] = (_Float16)v0.z; o[3] = (_Float16)v0.w;
    o[4] = (_Float16)v1.x; o[5] = (_Float16)v1.y;
    o[6] = (_Float16)v1.z; o[7] = (_Float16)v1.w;
    *(half8*)(Asw + (((size_t)tile * KC + kc) * 64 + lane) * 8) = o;
}

// ------------------------------------------------------------------
// All weight swizzles + bias concats in ONE dispatch.
// Blocks 0..183: 736 swizzle pairs (one wave each). Blocks 184..191: biases.
// ------------------------------------------------------------------
__global__ __launch_bounds__(256) void prep_weights(
    const float* __restrict__ s0, const float* __restrict__ s1,
    const float* __restrict__ s2, const float* __restrict__ s3,
    const float* __restrict__ s4, const float* __restrict__ s5,
    const float* __restrict__ s6, const float* __restrict__ s7,
    _Float16* __restrict__ catB0, _Float16* __restrict__ catB1,
    _Float16* __restrict__ catB2,
    const float* __restrict__ bl0, const float* __restrict__ br0,
    const float* __restrict__ pb0, const float* __restrict__ bl1,
    const float* __restrict__ br1, const float* __restrict__ bl2,
    const float* __restrict__ br2, const float* __restrict__ pb2,
    float* __restrict__ cb0, float* __restrict__ cb1, float* __restrict__ cb2)
{
    int b = blockIdx.x;
    if (b >= 184) {
        int t = (b - 184) * 256 + threadIdx.x;   // 0..2047
        if (t < 768) {
            cb0[t] = (t < 256) ? bl0[t] : (t < 512) ? br0[t - 256] : pb0[t - 512];
        } else if (t < 1280) {
            int u = t - 768;
            cb1[u] = (u < 256) ? bl1[u] : br1[u - 256];
        } else if (t < 1856) {
            int u = t - 1280;
            cb2[u] = (u < 256) ? bl2[u] : (u < 512) ? br2[u - 256] : pb2[u - 512];
        }
        return;
    }
    int wave = threadIdx.x >> 6, lane = threadIdx.x & 63;
    int pair = b * 4 + wave;     // 0..735
    const int cum[9] = {0, 64, 128, 192, 320, 448, 576, 704, 736};
    int job = 0;
    while (pair >= cum[job + 1]) ++job;
    const float* srcs[8] = {s0, s1, s2, s3, s4, s5, s6, s7};
    const int KCs[8] = {8, 8, 8, 16, 16, 16, 16, 16};
    const int NCs[8] = {256, 256, 256, 256, 256, 256, 256, 64};
    const int ntb[8] = {0, 8, 16, 0, 8, 0, 8, 16};
    _Float16* dsts[8] = {catB0, catB0, catB0, catB1, catB1, catB2, catB2, catB2};
    int p = pair - cum[job];
    int KC = KCs[job], NC = NCs[job];
    int nt = p / KC, kc = p - nt * KC;
    int n = nt * 32 + (lane & 31);
    int k0 = kc * 16 + (lane >> 5) * 8;
    const float* B = srcs[job];
    half8 o;
#pragma unroll
    for (int jj = 0; jj < 8; ++jj)
        o[jj] = (_Float16)B[(size_t)(k0 + jj) * NC + n];
    int ntG = ntb[job] + nt;
    *(half8*)(dsts[job] + (((size_t)ntG * KC + kc) * 64 + lane) * 8) = o;
}

// ------------------------------------------------------------------
// MFMA GEMM: C = A @ B + bias, fp16 pre-swizzled inputs, fp32 accum,
// fp16 output.
// ------------------------------------------------------------------
template<int CT>
__global__ __launch_bounds__(256) void gemm_mfma(
    const _Float16* __restrict__ Asw, const _Float16* __restrict__ Bsw,
    const float* __restrict__ bias, _Float16* __restrict__ C,
    int M, int K, int NC)
{
    const int wave = threadIdx.x >> 6, lane = threadIdx.x & 63;
    const int KC = K >> 4;
    const int rt0 = blockIdx.x * 4 + (wave & 1) * 2;
    const int ct0 = blockIdx.y * (2 * CT) + (wave >> 1) * CT;

    const half8* Ap0 = (const half8*)Asw + (size_t)rt0 * KC * 64 + lane;
    const half8* Ap1 = Ap0 + (size_t)KC * 64;
    const half8* Bp0 = (const half8*)Bsw + (size_t)ct0 * KC * 64 + lane;
    const half8* Bp1 = Bp0 + (size_t)KC * 64;

    floatx16 acc00 = {0.f}, acc10 = {0.f}, acc01 = {0.f}, acc11 = {0.f};

    for (int kc = 0; kc < KC; ++kc) {
        half8 a0 = Ap0[(size_t)kc * 64];
        half8 a1 = Ap1[(size_t)kc * 64];
        half8 b0 = Bp0[(size_t)kc * 64];
        acc00 = __builtin_amdgcn_mfma_f32_32x32x16_f16(a0, b0, acc00, 0, 0, 0);
        acc10 = __builtin_amdgcn_mfma_f32_32x32x16_f16(a1, b0, acc10, 0, 0, 0);
        if (CT == 2) {
            half8 b1 = Bp1[(size_t)kc * 64];
            acc01 = __builtin_amdgcn_mfma_f32_32x32x16_f16(a0, b1, acc01, 0, 0, 0);
            acc11 = __builtin_amdgcn_mfma_f32_32x32x16_f16(a1, b1, acc11, 0, 0, 0);
        }
    }

    const int nlane = lane & 31, hs = lane >> 5;
#pragma unroll
    for (int c = 0; c < CT; ++c) {
        int col = (ct0 + c) * 32 + nlane;
        float bb = bias[col];
        const floatx16& a_ = (c == 0) ? acc00 : acc01;
        const floatx16& b_ = (c == 0) ? acc10 : acc11;
#pragma unroll
        for (int r = 0; r < 16; ++r) {
            int rowin = (r & 3) + 8 * (r >> 2) + 4 * hs;
            int row0 = rt0 * 32 + rowin;
            int row1 = row0 + 32;
            if (row0 < M) C[(size_t)row0 * NC + col] = (_Float16)(a_[r] + bb);
            if (row1 < M) C[(size_t)row1 * NC + col] = (_Float16)(b_[r] + bb);
        }
    }
}

// ------------------------------------------------------------------
// CSR build: histogram -> two-level scan -> scatter
// ------------------------------------------------------------------
__global__ __launch_bounds__(256) void hist_kernel(const int* __restrict__ dst,
                                                   int* __restrict__ deg)
{
    int e = blockIdx.x * 256 + threadIdx.x;
    if (e < EE) atomicAdd(&deg[dst[e]], 1);
}

__global__ __launch_bounds__(256) void scan_local(const int* __restrict__ deg,
                                                  int* __restrict__ rowoff,
                                                  int* __restrict__ part)
{
    __shared__ int sd[256];
    int tid = threadIdx.x;
    int i = blockIdx.x * 256 + tid;
    int v = (i < NN) ? deg[i] : 0;
    sd[tid] = v;
    __syncthreads();
    for (int off = 1; off < 256; off <<= 1) {
        int t = (tid >= off) ? sd[tid - off] : 0;
        __syncthreads();
        sd[tid] += t;
        __syncthreads();
    }
    if (i < NN) rowoff[i] = sd[tid] - v;
    if (tid == 255) part[blockIdx.x] = sd[255];
}

__global__ __launch_bounds__(256) void scan_part(int* __restrict__ part,
                                                 int* __restrict__ rowoff)
{
    __shared__ int sd[256];
    int tid = threadIdx.x;
    int v = (tid < NB) ? part[tid] : 0;
    sd[tid] = v;
    __syncthreads();
    for (int off = 1; off < 256; off <<= 1) {
        int t = (tid >= off) ? sd[tid - off] : 0;
        __syncthreads();
        sd[tid] += t;
        __syncthreads();
    }
    if (tid < NB) part[tid] = sd[tid] - v;
    if (tid == 0) rowoff[NN] = EE;
}

__global__ __launch_bounds__(256) void scan_add(int* __restrict__ rowoff,
                                                const int* __restrict__ part,
                                                int* __restrict__ cursor)
{
    int i = blockIdx.x * 256 + threadIdx.x;
    if (i < NN) {
        rowoff[i] += part[blockIdx.x];
        cursor[i] = 0;
    }
}

__global__ __launch_bounds__(256) void scatter_kernel(
    const int* __restrict__ src, const int* __restrict__ dst,
    const float* __restrict__ ea, const int* __restrict__ rowoff,
    int* __restrict__ cursor, int* __restrict__ srcp,
    float4* __restrict__ eap, float* __restrict__ erec)
{
    int e = blockIdx.x * 256 + threadIdx.x;
    if (e < EE) {
        int d = dst[e];
        int pos = rowoff[d] + atomicAdd(&cursor[d], 1);
        srcp[pos] = src[e];
        const float* p = ea + (size_t)e * 5;
        eap[pos] = make_float4(p[0], p[1], p[2], p[3]);
        erec[pos] = 1.0f / fmaxf(p[3], 1e-6f);
    }
}

// ------------------------------------------------------------------
// Fused GATv2 + LayerNorm + residual (+ELU) + A-swizzle for next GEMM.
// One wave per node.
// mode 0: concat 256, fp16 resid slice, ELU; writes h (fp32) + Asw (fp16)
// mode 1: concat 256, fp32 resid (stride 256), ELU; writes Asw only
// mode 2: head-mean 64, fp16 resid slice, no ELU; writes outF (64-wide)
// ------------------------------------------------------------------
__global__ __launch_bounds__(256) void fused_attn_ln(
    const int* __restrict__ rowoff, const int* __restrict__ srcp,
    const float4* __restrict__ eap, const float* __restrict__ erec,
    const _Float16* __restrict__ xlp, int rstride,
    const float* __restrict__ We, const float* __restrict__ att,
    const float* __restrict__ temp, const float* __restrict__ bias,
    const float* __restrict__ lnw, const float* __restrict__ lnb,
    const _Float16* __restrict__ residH, const float* __restrict__ residF,
    float* __restrict__ outF, _Float16* __restrict__ aswOut, int mode)
{
    int v = __builtin_amdgcn_readfirstlane(blockIdx.x * 4 + (threadIdx.x >> 6));
    int lane = threadIdx.x & 63;
    if (v >= NN) return;
    int grp = lane >> 4;
    int sub = lane & 15;
    int j = grp * 64 + sub * 4;

    fv4 ww0 = *(const fv4*)(We + j);
    fv4 ww1 = *(const fv4*)(We + 256 + j);
    fv4 ww2 = *(const fv4*)(We + 512 + j);
    fv4 ww3 = *(const fv4*)(We + 768 + j);
    fv4 ww4 = *(const fv4*)(We + 1024 + j);
    fv4 atv = *(const fv4*)(att + j);
    fv4 xrv = __builtin_convertvector(
        *(const hv4*)(xlp + (size_t)v * rstride + 256 + j), fv4);
    float tmp = temp[0];
    const float L2E = 1.44269504088896340736f;

    float mxd = -INFINITY, dend = 0.f;
    fv4 acc = {0.f, 0.f, 0.f, 0.f};

    int beg = rowoff[v], end = rowoff[v + 1];
    int i = beg;
    for (; i + 2 <= end; i += 2) {
        int s0 = srcp[i], s1 = srcp[i + 1];
        float4 a0 = eap[i], a1 = eap[i + 1];
        float q0 = tmp * erec[i], q1 = tmp * erec[i + 1];
        fv4 x0 = __builtin_convertvector(
            *(const hv4*)(xlp + (size_t)s0 * rstride + j), fv4);
        fv4 x1 = __builtin_convertvector(
            *(const hv4*)(xlp + (size_t)s1 * rstride + j), fv4);
        fv4 m0 = x0 + xrv;
        m0 = m0 + a0.x * ww0; m0 = m0 + a0.y * ww1; m0 = m0 + a0.z * ww2;
        m0 = m0 + a0.w * ww3; m0 = m0 + q0 * ww4;
        fv4 m1 = x1 + xrv;
        m1 = m1 + a1.x * ww0; m1 = m1 + a1.y * ww1; m1 = m1 + a1.z * ww2;
        m1 = m1 + a1.w * ww3; m1 = m1 + q1 * ww4;
        m0 = __builtin_elementwise_max(m0, m0 * 0.2f);
        m1 = __builtin_elementwise_max(m1, m1 * 0.2f);
        fv4 p0 = m0 * atv, p1 = m1 * atv;
        float l0 = (p0[0] + p0[1]) + (p0[2] + p0[3]);
        float l1 = (p1[0] + p1[1]) + (p1[2] + p1[3]);
        l0 = red16(l0) * L2E;
        l1 = red16(l1) * L2E;
        float nm = fmaxf(mxd, fmaxf(l0, l1));
        float sc = fexp2(mxd - nm);
        float e0 = fexp2(l0 - nm);
        float e1 = fexp2(l1 - nm);
        mxd = nm;
        dend = dend * sc + (e0 + e1);
        acc = acc * sc + (x0 * e0 + x1 * e1);
    }
    if (i < end) {
        int s0 = srcp[i];
        float4 a0 = eap[i];
        float q0 = tmp * erec[i];
        fv4 x0 = __builtin_convertvector(
            *(const hv4*)(xlp + (size_t)s0 * rstride + j), fv4);
        fv4 m0 = x0 + xrv;
        m0 = m0 + a0.x * ww0; m0 = m0 + a0.y * ww1; m0 = m0 + a0.z * ww2;
        m0 = m0 + a0.w * ww3; m0 = m0 + q0 * ww4;
        m0 = __builtin_elementwise_max(m0, m0 * 0.2f);
        fv4 p0 = m0 * atv;
        float l0 = (p0[0] + p0[1]) + (p0[2] + p0[3]);
        l0 = red16(l0) * L2E;
        float nm = fmaxf(mxd, l0);
        float sc = fexp2(mxd - nm);
        float e0 = fexp2(l0 - nm);
        mxd = nm;
        dend = dend * sc + e0;
        acc = acc * sc + x0 * e0;
    }

    float inv = __builtin_amdgcn_rcpf(dend + 1e-16f);
    if (mode <= 1) {
        fv4 bb = *(const fv4*)(bias + j);
        fv4 o = acc * inv + bb;
        float s  = (o[0] + o[1]) + (o[2] + o[3]);
        fv4 oq = o * o;
        float s2 = (oq[0] + oq[1]) + (oq[2] + oq[3]);
        s = red16(s);   s += __shfl_xor(s, 16, 64);  s += __shfl_xor(s, 32, 64);
        s2 = red16(s2); s2 += __shfl_xor(s2, 16, 64); s2 += __shfl_xor(s2, 32, 64);
        float mu = s * (1.f / 256.f);
        float var = s2 * (1.f / 256.f) - mu * mu;
        float rs = __builtin_amdgcn_rsqf(var + 1e-5f);
        fv4 lw = *(const fv4*)(lnw + j);
        fv4 lb = *(const fv4*)(lnb + j);
        fv4 rr;
        if (mode == 0)
            rr = __builtin_convertvector(
                *(const hv4*)(residH + (size_t)v * rstride + j), fv4);
        else
            rr = *(const fv4*)(residF + (size_t)v * 256 + j);
        fv4 y = (o - mu) * rs * lw + lb + rr;
        y[0] = (y[0] > 0.f) ? y[0] : fexp2(y[0] * L2E) - 1.f;
        y[1] = (y[1] > 0.f) ? y[1] : fexp2(y[1] * L2E) - 1.f;
        y[2] = (y[2] > 0.f) ? y[2] : fexp2(y[2] * L2E) - 1.f;
        y[3] = (y[3] > 0.f) ? y[3] : fexp2(y[3] * L2E) - 1.f;
        if (mode == 0)
            *(fv4*)(outF + (size_t)v * 256 + j) = y;
        // fused A-swizzle for the next layer's GEMM (K=256, KC=16)
        int kc = j >> 4, half = (j >> 3) & 1, off = j & 7;
        size_t idx = (((size_t)(v >> 5) * 16 + kc) * 64 + (v & 31) + 32 * half) * 8 + off;
        hv4 yh = __builtin_convertvector(y, hv4);
        *(hv4*)(aswOut + idx) = yh;
    } else {
        fv4 r = acc * inv;
        r[0] += __shfl_xor(r[0], 16, 64); r[0] += __shfl_xor(r[0], 32, 64);
        r[1] += __shfl_xor(r[1], 16, 64); r[1] += __shfl_xor(r[1], 32, 64);
        r[2] += __shfl_xor(r[2], 16, 64); r[2] += __shfl_xor(r[2], 32, 64);
        r[3] += __shfl_xor(r[3], 16, 64); r[3] += __shfl_xor(r[3], 32, 64);
        fv4 bb = *(const fv4*)(bias + sub * 4);
        fv4 o = r * 0.25f + bb;
        float s  = (o[0] + o[1]) + (o[2] + o[3]);
        fv4 oq = o * o;
        float s2 = (oq[0] + oq[1]) + (oq[2] + oq[3]);
        s = red16(s);
        s2 = red16(s2);
        float mu = s * (1.f / 64.f);
        float var = s2 * (1.f / 64.f) - mu * mu;
        float rs = __builtin_amdgcn_rsqf(var + 1e-5f);
        fv4 lw = *(const fv4*)(lnw + sub * 4);
        fv4 lb = *(const fv4*)(lnb + sub * 4);
        fv4 rr = __builtin_convertvector(
            *(const hv4*)(residH + (size_t)v * rstride + sub * 4), fv4);
        fv4 y = (o - mu) * rs * lw + lb + rr;
        if (grp == 0)
            *(fv4*)(outF + (size_t)v * 64 + sub * 4) = y;
    }
}

// ------------------------------------------------------------------
extern "C" void kernel_launch(void* const* d_in, const int* in_sizes, int n_in,
                              void* d_out, int out_size, void* d_ws, size_t ws_size,
                              hipStream_t stream)
{
    const float* x    = (const float*)d_in[0];
    const int*   eidx = (const int*)d_in[1];
    const float* ea   = (const float*)d_in[2];
    const int* src = eidx;
    const int* dst = eidx + EE;

    const float *Wl[3], *bl[3], *Wr[3], *br[3], *We[3], *att[3], *temp[3],
                *bias[3], *lnw[3], *lnb[3];
    for (int i = 0; i < 3; ++i) {
        int b = 3 + i * 10;
        Wl[i]   = (const float*)d_in[b + 0];
        bl[i]   = (const float*)d_in[b + 1];
        Wr[i]   = (const float*)d_in[b + 2];
        br[i]   = (const float*)d_in[b + 3];
        We[i]   = (const float*)d_in[b + 4];
        att[i]  = (const float*)d_in[b + 5];
        temp[i] = (const float*)d_in[b + 6];
        bias[i] = (const float*)d_in[b + 7];
        lnw[i]  = (const float*)d_in[b + 8];
        lnb[i]  = (const float*)d_in[b + 9];
    }
    const float* pw0 = (const float*)d_in[33];
    const float* pb0 = (const float*)d_in[34];
    const float* pw2 = (const float*)d_in[35];
    const float* pb2 = (const float*)d_in[36];

    // workspace carve-up
    char* w = (char*)d_ws;
    float* h     = (float*)w; w += (size_t)NN * 256 * 4;          // 51.2 MB
    char*  gbase = w;         w += (size_t)NN * 256 * 4;          // Asw region
    _Float16* xlr = (_Float16*)w; w += (size_t)NN * 768 * 2;      // 76.8 MB
    float4* eap  = (float4*)w; w += (size_t)EE * 16;
    float* erec  = (float*)w; w += (size_t)EE * 4;
    int* srcp    = (int*)w;   w += (size_t)EE * 4;
    int* rowoff  = (int*)w;   w += (size_t)(NN + 16) * 4;
    int* cursor  = (int*)w;   w += (size_t)NN * 4;
    int* part    = (int*)w;   w += 1024;
    w = (char*)(((uintptr_t)w + 255) & ~(uintptr_t)255);
    _Float16* catB0 = (_Float16*)w; w += 196608;   // 24 nt x  8 kc x 512 h
    _Float16* catB1 = (_Float16*)w; w += 262144;   // 16 nt x 16 kc
    _Float16* catB2 = (_Float16*)w; w += 294912;   // 18 nt x 16 kc
    float* cb0 = (float*)w; w += 768 * 4;
    float* cb1 = (float*)w; w += 512 * 4;
    float* cb2 = (float*)w; w += 576 * 4;
    _Float16* Asw = (_Float16*)gbase;              // <= 25.7 MB

    dim3 blk(256);
    dim3 grid_e((EE + 255) / 256);
    dim3 grid_nw((NN + 3) / 4);
    dim3 grid_nb(NB);
    const int MT = 391;   // ceil(50000/128)

    auto attn = [&](int L, int rstride, const _Float16* residH,
                    const float* residF, float* outFp, _Float16* asw, int mode) {
        fused_attn_ln<<<grid_nw, blk, 0, stream>>>(
            rowoff, srcp, eap, erec, xlr, rstride, We[L], att[L], temp[L],
            bias[L], lnw[L], lnb[L], residH, residF, outFp, asw, mode);
    };

    // ---- CSR by dst (shared by all 3 layers) ----
    hipMemsetAsync(cursor, 0, (size_t)NN * 4, stream);
    hipLaunchKernelGGL(hist_kernel, grid_e, blk, 0, stream, dst, cursor);
    hipLaunchKernelGGL(scan_local, grid_nb, blk, 0, stream, cursor, rowoff, part);
    hipLaunchKernelGGL(scan_part, dim3(1), blk, 0, stream, part, rowoff);
    hipLaunchKernelGGL(scan_add, grid_nb, blk, 0, stream, rowoff, part, cursor);
    hipLaunchKernelGGL(scatter_kernel, grid_e, blk, 0, stream,
                       src, dst, ea, rowoff, cursor, srcp, eap, erec);

    // ---- all weight swizzles + bias concats, one dispatch ----
    hipLaunchKernelGGL(prep_weights, dim3(192), blk, 0, stream,
                       Wl[0], Wr[0], pw0, Wl[1], Wr[1], Wl[2], Wr[2], pw2,
                       catB0, catB1, catB2,
                       bl[0], br[0], pb0, bl[1], br[1], bl[2], br[2], pb2,
                       cb0, cb1, cb2);

    // ---- Layer 0: swizzle x, one GEMM -> [xl|xr|res] fp16 rows of 768 ----
    swizzleA<<<dim3(4 * MT, 2), blk, 0, stream>>>(x, Asw, NN, 128);
    gemm_mfma<2><<<dim3(MT, 6), blk, 0, stream>>>(
        Asw, catB0, cb0, xlr, NN, 128, 768);
    // GAT + LN256 + resid(fp16 slice) + ELU -> h (fp32) + Asw (fp16, K=256)
    attn(0, 768, xlr + 512, nullptr, h, Asw, 0);

    // ---- Layer 1: one GEMM -> [xl|xr] rows of 512; resid = h ----
    gemm_mfma<2><<<dim3(MT, 4), blk, 0, stream>>>(
        Asw, catB1, cb1, xlr, NN, 256, 512);
    attn(1, 512, nullptr, h, nullptr, Asw, 1);   // writes Asw only

    // ---- Layer 2: [xl|xr|res64] rows of 576 (two GEMM dispatches) ----
    gemm_mfma<2><<<dim3(MT, 4), blk, 0, stream>>>(
        Asw, catB2, cb2, xlr, NN, 256, 576);
    gemm_mfma<1><<<dim3(MT, 1), blk, 0, stream>>>(
        Asw, catB2 + 131072, cb2 + 512, xlr + 512, NN, 256, 576);
    attn(2, 576, xlr + 512, nullptr, (float*)d_out, nullptr, 2);
}

// Round 8
// 656.254 us; speedup vs baseline: 3.3304x; 1.0779x over previous
//
#include <hip/hip_runtime.h>
#include <math.h>

#define NN 50000
#define EE 800000
#define NB 196   // ceil(NN/256)

typedef _Float16 half8 __attribute__((ext_vector_type(8)));
typedef _Float16 hv4  __attribute__((ext_vector_type(4)));
typedef _Float16 hv2  __attribute__((ext_vector_type(2)));
typedef float floatx16 __attribute__((ext_vector_type(16)));
typedef float fv4 __attribute__((ext_vector_type(4)));

__device__ __forceinline__ float fexp2(float x) { return __builtin_amdgcn_exp2f(x); }

// DPP row_ror all-reduce within 16-lane rows: rotations by 1,2,4,8.
template<int CTRL>
__device__ __forceinline__ float dppadd(float x) {
    int t = __builtin_amdgcn_update_dpp(0, __float_as_int(x), CTRL, 0xf, 0xf, false);
    return x + __int_as_float(t);
}
__device__ __forceinline__ float red16(float x) {
    x = dppadd<0x121>(x);   // row_ror:1
    x = dppadd<0x122>(x);   // row_ror:2
    x = dppadd<0x124>(x);   // row_ror:4
    x = dppadd<0x128>(x);   // row_ror:8
    return x;
}

// ------------------------------------------------------------------
// Swizzle A (fp32 row-major M x K) into 32x32x16 MFMA A-fragment order.
// Used only for the input x (K=128); later layers fuse this into attn.
// ------------------------------------------------------------------
__global__ __launch_bounds__(256) void swizzleA(
    const float* __restrict__ A, _Float16* __restrict__ Asw, int M, int K)
{
    int wave = threadIdx.x >> 6, lane = threadIdx.x & 63;
    int tile = blockIdx.x;
    int kc = blockIdx.y * 4 + wave;
    int KC = K >> 4;
    int row = tile * 32 + (lane & 31);
    int k0 = kc * 16 + (lane >> 5) * 8;
    float4 v0 = make_float4(0.f, 0.f, 0.f, 0.f);
    float4 v1 = make_float4(0.f, 0.f, 0.f, 0.f);
    if (row < M) {
        const float* p = A + (size_t)row * K + k0;
        v0 = *(const float4*)p;
        v1 = *(const float4*)(p + 4);
    }
    half8 o;
    o[0] = (_Float16)v0.x; o[1] = (_Float16)v0.y;
    o[2] = (_Float16)v0.z; o[3] = (_Float16)v0.w;
    o[4] = (_Float16)v1.x; o[5] = (_Float16)v1.y;
    o[6] = (_Float16)v1.z; o[7] = (_Float16)v1.w;
    *(half8*)(Asw + (((size_t)tile * KC + kc) * 64 + lane) * 8) = o;
}

// ------------------------------------------------------------------
// All weight swizzles + bias concats in ONE dispatch.
// Columns are even/odd interleaved per 64-col group: tile 2g holds even
// cols of group g, tile 2g+1 holds odd cols -> GEMM epilogue packs pairs.
// Blocks 0..183: 736 swizzle pairs (one wave each). Blocks 184..191: biases.
// ------------------------------------------------------------------
__global__ __launch_bounds__(256) void prep_weights(
    const float* __restrict__ s0, const float* __restrict__ s1,
    const float* __restrict__ s2, const float* __restrict__ s3,
    const float* __restrict__ s4, const float* __restrict__ s5,
    const float* __restrict__ s6, const float* __restrict__ s7,
    _Float16* __restrict__ catB0, _Float16* __restrict__ catB1,
    _Float16* __restrict__ catB2,
    const float* __restrict__ bl0, const float* __restrict__ br0,
    const float* __restrict__ pb0, const float* __restrict__ bl1,
    const float* __restrict__ br1, const float* __restrict__ bl2,
    const float* __restrict__ br2, const float* __restrict__ pb2,
    float* __restrict__ cb0, float* __restrict__ cb1, float* __restrict__ cb2)
{
    int b = blockIdx.x;
    if (b >= 184) {
        int t = (b - 184) * 256 + threadIdx.x;   // 0..2047
        if (t < 768) {
            cb0[t] = (t < 256) ? bl0[t] : (t < 512) ? br0[t - 256] : pb0[t - 512];
        } else if (t < 1280) {
            int u = t - 768;
            cb1[u] = (u < 256) ? bl1[u] : br1[u - 256];
        } else if (t < 1856) {
            int u = t - 1280;
            cb2[u] = (u < 256) ? bl2[u] : (u < 512) ? br2[u - 256] : pb2[u - 512];
        }
        return;
    }
    int wave = threadIdx.x >> 6, lane = threadIdx.x & 63;
    int pair = b * 4 + wave;     // 0..735
    const int cum[9] = {0, 64, 128, 192, 320, 448, 576, 704, 736};
    int job = 0;
    while (pair >= cum[job + 1]) ++job;
    const float* srcs[8] = {s0, s1, s2, s3, s4, s5, s6, s7};
    const int KCs[8] = {8, 8, 8, 16, 16, 16, 16, 16};
    const int NCs[8] = {256, 256, 256, 256, 256, 256, 256, 64};
    const int ntb[8] = {0, 8, 16, 0, 8, 0, 8, 16};
    _Float16* dsts[8] = {catB0, catB0, catB0, catB1, catB1, catB2, catB2, catB2};
    int p = pair - cum[job];
    int KC = KCs[job], NC = NCs[job];
    int nt = p / KC, kc = p - nt * KC;
    // even/odd interleave within the 64-col group
    int n = (nt >> 1) * 64 + ((lane & 31) * 2) + (nt & 1);
    int k0 = kc * 16 + (lane >> 5) * 8;
    const float* B = srcs[job];
    half8 o;
#pragma unroll
    for (int jj = 0; jj < 8; ++jj)
        o[jj] = (_Float16)B[(size_t)(k0 + jj) * NC + n];
    int ntG = ntb[job] + nt;
    *(half8*)(dsts[job] + (((size_t)ntG * KC + kc) * 64 + lane) * 8) = o;
}

// ------------------------------------------------------------------
// MFMA GEMM: C = A @ B + bias, fp16 pre-swizzled inputs, fp32 accum,
// fp16 output. Each wave-pair handles one 64-col group (even/odd tile
// pair); epilogue packs (even,odd) into one 4B store -> 128B segments.
// ------------------------------------------------------------------
__global__ __launch_bounds__(256) void gemm_mfma(
    const _Float16* __restrict__ Asw, const _Float16* __restrict__ Bsw,
    const float* __restrict__ bias, _Float16* __restrict__ C,
    int M, int K, int NC)
{
    const int wave = threadIdx.x >> 6, lane = threadIdx.x & 63;
    const int KC = K >> 4;
    const int rt0 = blockIdx.x * 4 + (wave & 1) * 2;
    const int NG = NC >> 6;
    int g = blockIdx.y * 2 + (wave >> 1);
    if (g >= NG) g = NG - 1;      // duplicate work for odd group counts

    const half8* Ap0 = (const half8*)Asw + (size_t)rt0 * KC * 64 + lane;
    const half8* Ap1 = Ap0 + (size_t)KC * 64;
    const half8* Bp0 = (const half8*)Bsw + (size_t)(2 * g) * KC * 64 + lane;
    const half8* Bp1 = Bp0 + (size_t)KC * 64;

    floatx16 accE0 = {0.f}, accE1 = {0.f}, accO0 = {0.f}, accO1 = {0.f};

#pragma unroll 4
    for (int kc = 0; kc < KC; ++kc) {
        half8 a0 = Ap0[(size_t)kc * 64];
        half8 a1 = Ap1[(size_t)kc * 64];
        half8 b0 = Bp0[(size_t)kc * 64];
        half8 b1 = Bp1[(size_t)kc * 64];
        accE0 = __builtin_amdgcn_mfma_f32_32x32x16_f16(a0, b0, accE0, 0, 0, 0);
        accE1 = __builtin_amdgcn_mfma_f32_32x32x16_f16(a1, b0, accE1, 0, 0, 0);
        accO0 = __builtin_amdgcn_mfma_f32_32x32x16_f16(a0, b1, accO0, 0, 0, 0);
        accO1 = __builtin_amdgcn_mfma_f32_32x32x16_f16(a1, b1, accO1, 0, 0, 0);
    }

    const int nlane = lane & 31, hs = lane >> 5;
    int colb = g * 64 + nlane * 2;
    float be = bias[colb], bo = bias[colb + 1];
#pragma unroll
    for (int r = 0; r < 16; ++r) {
        int rowin = (r & 3) + 8 * (r >> 2) + 4 * hs;
        int row0 = rt0 * 32 + rowin;
        int row1 = row0 + 32;
        if (row0 < M) {
            hv2 pe;
            pe[0] = (_Float16)(accE0[r] + be);
            pe[1] = (_Float16)(accO0[r] + bo);
            *(hv2*)(C + (size_t)row0 * NC + colb) = pe;
        }
        if (row1 < M) {
            hv2 po;
            po[0] = (_Float16)(accE1[r] + be);
            po[1] = (_Float16)(accO1[r] + bo);
            *(hv2*)(C + (size_t)row1 * NC + colb) = po;
        }
    }
}

// ------------------------------------------------------------------
// CSR build: histogram -> two-level scan -> scatter
// ------------------------------------------------------------------
__global__ __launch_bounds__(256) void hist_kernel(const int* __restrict__ dst,
                                                   int* __restrict__ deg)
{
    int e = blockIdx.x * 256 + threadIdx.x;
    if (e < EE) atomicAdd(&deg[dst[e]], 1);
}

__global__ __launch_bounds__(256) void scan_local(const int* __restrict__ deg,
                                                  int* __restrict__ rowoff,
                                                  int* __restrict__ part)
{
    __shared__ int sd[256];
    int tid = threadIdx.x;
    int i = blockIdx.x * 256 + tid;
    int v = (i < NN) ? deg[i] : 0;
    sd[tid] = v;
    __syncthreads();
    for (int off = 1; off < 256; off <<= 1) {
        int t = (tid >= off) ? sd[tid - off] : 0;
        __syncthreads();
        sd[tid] += t;
        __syncthreads();
    }
    if (i < NN) rowoff[i] = sd[tid] - v;
    if (tid == 255) part[blockIdx.x] = sd[255];
}

__global__ __launch_bounds__(256) void scan_part(int* __restrict__ part,
                                                 int* __restrict__ rowoff)
{
    __shared__ int sd[256];
    int tid = threadIdx.x;
    int v = (tid < NB) ? part[tid] : 0;
    sd[tid] = v;
    __syncthreads();
    for (int off = 1; off < 256; off <<= 1) {
        int t = (tid >= off) ? sd[tid - off] : 0;
        __syncthreads();
        sd[tid] += t;
        __syncthreads();
    }
    if (tid < NB) part[tid] = sd[tid] - v;
    if (tid == 0) rowoff[NN] = EE;
}

__global__ __launch_bounds__(256) void scan_add(int* __restrict__ rowoff,
                                                const int* __restrict__ part,
                                                int* __restrict__ cursor)
{
    int i = blockIdx.x * 256 + threadIdx.x;
    if (i < NN) {
        rowoff[i] += part[blockIdx.x];
        cursor[i] = 0;
    }
}

__global__ __launch_bounds__(256) void scatter_kernel(
    const int* __restrict__ src, const int* __restrict__ dst,
    const float* __restrict__ ea, const int* __restrict__ rowoff,
    int* __restrict__ cursor, int* __restrict__ srcp,
    float4* __restrict__ eap, float* __restrict__ erec)
{
    int e = blockIdx.x * 256 + threadIdx.x;
    if (e < EE) {
        int d = dst[e];
        int pos = rowoff[d] + atomicAdd(&cursor[d], 1);
        srcp[pos] = src[e];
        const float* p = ea + (size_t)e * 5;
        eap[pos] = make_float4(p[0], p[1], p[2], p[3]);
        erec[pos] = 1.0f / fmaxf(p[3], 1e-6f);
    }
}

// ------------------------------------------------------------------
// Fused GATv2 + LayerNorm + residual (+ELU) + A-swizzle for next GEMM.
// One wave per node, edge loop unrolled x4.
// mode 0: concat 256, fp16 resid slice, ELU; writes h (fp32) + Asw (fp16)
// mode 1: concat 256, fp32 resid (stride 256), ELU; writes Asw only
// mode 2: head-mean 64, fp16 resid slice, no ELU; writes outF (64-wide)
// ------------------------------------------------------------------
__global__ __launch_bounds__(256) void fused_attn_ln(
    const int* __restrict__ rowoff, const int* __restrict__ srcp,
    const float4* __restrict__ eap, const float* __restrict__ erec,
    const _Float16* __restrict__ xlp, int rstride,
    const float* __restrict__ We, const float* __restrict__ att,
    const float* __restrict__ temp, const float* __restrict__ bias,
    const float* __restrict__ lnw, const float* __restrict__ lnb,
    const _Float16* __restrict__ residH, const float* __restrict__ residF,
    float* __restrict__ outF, _Float16* __restrict__ aswOut, int mode)
{
    int v = __builtin_amdgcn_readfirstlane(blockIdx.x * 4 + (threadIdx.x >> 6));
    int lane = threadIdx.x & 63;
    if (v >= NN) return;
    int grp = lane >> 4;
    int sub = lane & 15;
    int j = grp * 64 + sub * 4;

    fv4 ww0 = *(const fv4*)(We + j);
    fv4 ww1 = *(const fv4*)(We + 256 + j);
    fv4 ww2 = *(const fv4*)(We + 512 + j);
    fv4 ww3 = *(const fv4*)(We + 768 + j);
    fv4 ww4 = *(const fv4*)(We + 1024 + j);
    fv4 atv = *(const fv4*)(att + j);
    fv4 xrv = __builtin_convertvector(
        *(const hv4*)(xlp + (size_t)v * rstride + 256 + j), fv4);
    float tmp = temp[0];
    const float L2E = 1.44269504088896340736f;

    float mxd = -INFINITY, dend = 0.f;
    fv4 acc = {0.f, 0.f, 0.f, 0.f};

    int beg = rowoff[v], end = rowoff[v + 1];
    int i = beg;
    for (; i + 4 <= end; i += 4) {
        int s[4]; float4 a[4]; float q[4]; fv4 xv[4]; float l[4];
#pragma unroll
        for (int u = 0; u < 4; ++u) {
            s[u] = srcp[i + u];
            a[u] = eap[i + u];
            q[u] = tmp * erec[i + u];
        }
#pragma unroll
        for (int u = 0; u < 4; ++u)
            xv[u] = __builtin_convertvector(
                *(const hv4*)(xlp + (size_t)s[u] * rstride + j), fv4);
#pragma unroll
        for (int u = 0; u < 4; ++u) {
            fv4 m = xv[u] + xrv;
            m = m + a[u].x * ww0; m = m + a[u].y * ww1; m = m + a[u].z * ww2;
            m = m + a[u].w * ww3; m = m + q[u] * ww4;
            m = __builtin_elementwise_max(m, m * 0.2f);
            fv4 p = m * atv;
            l[u] = (p[0] + p[1]) + (p[2] + p[3]);
        }
#pragma unroll
        for (int u = 0; u < 4; ++u) l[u] = red16(l[u]) * L2E;
        float nm = fmaxf(fmaxf(l[0], l[1]), fmaxf(l[2], l[3]));
        nm = fmaxf(nm, mxd);
        float sc = fexp2(mxd - nm);
        float e0 = fexp2(l[0] - nm);
        float e1 = fexp2(l[1] - nm);
        float e2 = fexp2(l[2] - nm);
        float e3 = fexp2(l[3] - nm);
        mxd = nm;
        dend = dend * sc + ((e0 + e1) + (e2 + e3));
        acc = acc * sc +
              ((xv[0] * e0 + xv[1] * e1) + (xv[2] * e2 + xv[3] * e3));
    }
    for (; i < end; ++i) {
        int s0 = srcp[i];
        float4 a0 = eap[i];
        float q0 = tmp * erec[i];
        fv4 x0 = __builtin_convertvector(
            *(const hv4*)(xlp + (size_t)s0 * rstride + j), fv4);
        fv4 m0 = x0 + xrv;
        m0 = m0 + a0.x * ww0; m0 = m0 + a0.y * ww1; m0 = m0 + a0.z * ww2;
        m0 = m0 + a0.w * ww3; m0 = m0 + q0 * ww4;
        m0 = __builtin_elementwise_max(m0, m0 * 0.2f);
        fv4 p0 = m0 * atv;
        float l0 = (p0[0] + p0[1]) + (p0[2] + p0[3]);
        l0 = red16(l0) * L2E;
        float nm = fmaxf(mxd, l0);
        float sc = fexp2(mxd - nm);
        float e0 = fexp2(l0 - nm);
        mxd = nm;
        dend = dend * sc + e0;
        acc = acc * sc + x0 * e0;
    }

    float inv = __builtin_amdgcn_rcpf(dend + 1e-16f);
    if (mode <= 1) {
        fv4 bb = *(const fv4*)(bias + j);
        fv4 o = acc * inv + bb;
        float s  = (o[0] + o[1]) + (o[2] + o[3]);
        fv4 oq = o * o;
        float s2 = (oq[0] + oq[1]) + (oq[2] + oq[3]);
        s = red16(s);   s += __shfl_xor(s, 16, 64);  s += __shfl_xor(s, 32, 64);
        s2 = red16(s2); s2 += __shfl_xor(s2, 16, 64); s2 += __shfl_xor(s2, 32, 64);
        float mu = s * (1.f / 256.f);
        float var = s2 * (1.f / 256.f) - mu * mu;
        float rs = __builtin_amdgcn_rsqf(var + 1e-5f);
        fv4 lw = *(const fv4*)(lnw + j);
        fv4 lb = *(const fv4*)(lnb + j);
        fv4 rr;
        if (mode == 0)
            rr = __builtin_convertvector(
                *(const hv4*)(residH + (size_t)v * rstride + j), fv4);
        else
            rr = *(const fv4*)(residF + (size_t)v * 256 + j);
        fv4 y = (o - mu) * rs * lw + lb + rr;
        y[0] = (y[0] > 0.f) ? y[0] : fexp2(y[0] * L2E) - 1.f;
        y[1] = (y[1] > 0.f) ? y[1] : fexp2(y[1] * L2E) - 1.f;
        y[2] = (y[2] > 0.f) ? y[2] : fexp2(y[2] * L2E) - 1.f;
        y[3] = (y[3] > 0.f) ? y[3] : fexp2(y[3] * L2E) - 1.f;
        if (mode == 0)
            *(fv4*)(outF + (size_t)v * 256 + j) = y;
        // fused A-swizzle for the next layer's GEMM (K=256, KC=16)
        int kc = j >> 4, half = (j >> 3) & 1, off = j & 7;
        size_t idx = (((size_t)(v >> 5) * 16 + kc) * 64 + (v & 31) + 32 * half) * 8 + off;
        hv4 yh = __builtin_convertvector(y, hv4);
        *(hv4*)(aswOut + idx) = yh;
    } else {
        fv4 r = acc * inv;
        r[0] += __shfl_xor(r[0], 16, 64); r[0] += __shfl_xor(r[0], 32, 64);
        r[1] += __shfl_xor(r[1], 16, 64); r[1] += __shfl_xor(r[1], 32, 64);
        r[2] += __shfl_xor(r[2], 16, 64); r[2] += __shfl_xor(r[2], 32, 64);
        r[3] += __shfl_xor(r[3], 16, 64); r[3] += __shfl_xor(r[3], 32, 64);
        fv4 bb = *(const fv4*)(bias + sub * 4);
        fv4 o = r * 0.25f + bb;
        float s  = (o[0] + o[1]) + (o[2] + o[3]);
        fv4 oq = o * o;
        float s2 = (oq[0] + oq[1]) + (oq[2] + oq[3]);
        s = red16(s);
        s2 = red16(s2);
        float mu = s * (1.f / 64.f);
        float var = s2 * (1.f / 64.f) - mu * mu;
        float rs = __builtin_amdgcn_rsqf(var + 1e-5f);
        fv4 lw = *(const fv4*)(lnw + sub * 4);
        fv4 lb = *(const fv4*)(lnb + sub * 4);
        fv4 rr = __builtin_convertvector(
            *(const hv4*)(residH + (size_t)v * rstride + sub * 4), fv4);
        fv4 y = (o - mu) * rs * lw + lb + rr;
        if (grp == 0)
            *(fv4*)(outF + (size_t)v * 64 + sub * 4) = y;
    }
}

// ------------------------------------------------------------------
extern "C" void kernel_launch(void* const* d_in, const int* in_sizes, int n_in,
                              void* d_out, int out_size, void* d_ws, size_t ws_size,
                              hipStream_t stream)
{
    const float* x    = (const float*)d_in[0];
    const int*   eidx = (const int*)d_in[1];
    const float* ea   = (const float*)d_in[2];
    const int* src = eidx;
    const int* dst = eidx + EE;

    const float *Wl[3], *bl[3], *Wr[3], *br[3], *We[3], *att[3], *temp[3],
                *bias[3], *lnw[3], *lnb[3];
    for (int i = 0; i < 3; ++i) {
        int b = 3 + i * 10;
        Wl[i]   = (const float*)d_in[b + 0];
        bl[i]   = (const float*)d_in[b + 1];
        Wr[i]   = (const float*)d_in[b + 2];
        br[i]   = (const float*)d_in[b + 3];
        We[i]   = (const float*)d_in[b + 4];
        att[i]  = (const float*)d_in[b + 5];
        temp[i] = (const float*)d_in[b + 6];
        bias[i] = (const float*)d_in[b + 7];
        lnw[i]  = (const float*)d_in[b + 8];
        lnb[i]  = (const float*)d_in[b + 9];
    }
    const float* pw0 = (const float*)d_in[33];
    const float* pb0 = (const float*)d_in[34];
    const float* pw2 = (const float*)d_in[35];
    const float* pb2 = (const float*)d_in[36];

    // workspace carve-up
    char* w = (char*)d_ws;
    float* h     = (float*)w; w += (size_t)NN * 256 * 4;          // 51.2 MB
    char*  gbase = w;         w += (size_t)NN * 256 * 4;          // Asw region
    _Float16* xlr = (_Float16*)w; w += (size_t)NN * 768 * 2;      // 76.8 MB
    float4* eap  = (float4*)w; w += (size_t)EE * 16;
    float* erec  = (float*)w; w += (size_t)EE * 4;
    int* srcp    = (int*)w;   w += (size_t)EE * 4;
    int* rowoff  = (int*)w;   w += (size_t)(NN + 16) * 4;
    int* cursor  = (int*)w;   w += (size_t)NN * 4;
    int* part    = (int*)w;   w += 1024;
    w = (char*)(((uintptr_t)w + 255) & ~(uintptr_t)255);
    _Float16* catB0 = (_Float16*)w; w += 196608;   // 24 nt x  8 kc x 512 h
    _Float16* catB1 = (_Float16*)w; w += 262144;   // 16 nt x 16 kc
    _Float16* catB2 = (_Float16*)w; w += 294912;   // 18 nt x 16 kc
    float* cb0 = (float*)w; w += 768 * 4;
    float* cb1 = (float*)w; w += 512 * 4;
    float* cb2 = (float*)w; w += 576 * 4;
    _Float16* Asw = (_Float16*)gbase;              // <= 25.7 MB

    dim3 blk(256);
    dim3 grid_e((EE + 255) / 256);
    dim3 grid_nw((NN + 3) / 4);
    dim3 grid_nb(NB);
    const int MT = 391;   // ceil(50000/128)

    auto attn = [&](int L, int rstride, const _Float16* residH,
                    const float* residF, float* outFp, _Float16* asw, int mode) {
        fused_attn_ln<<<grid_nw, blk, 0, stream>>>(
            rowoff, srcp, eap, erec, xlr, rstride, We[L], att[L], temp[L],
            bias[L], lnw[L], lnb[L], residH, residF, outFp, asw, mode);
    };

    // ---- CSR by dst (shared by all 3 layers) ----
    hipMemsetAsync(cursor, 0, (size_t)NN * 4, stream);
    hipLaunchKernelGGL(hist_kernel, grid_e, blk, 0, stream, dst, cursor);
    hipLaunchKernelGGL(scan_local, grid_nb, blk, 0, stream, cursor, rowoff, part);
    hipLaunchKernelGGL(scan_part, dim3(1), blk, 0, stream, part, rowoff);
    hipLaunchKernelGGL(scan_add, grid_nb, blk, 0, stream, rowoff, part, cursor);
    hipLaunchKernelGGL(scatter_kernel, grid_e, blk, 0, stream,
                       src, dst, ea, rowoff, cursor, srcp, eap, erec);

    // ---- all weight swizzles + bias concats, one dispatch ----
    hipLaunchKernelGGL(prep_weights, dim3(192), blk, 0, stream,
                       Wl[0], Wr[0], pw0, Wl[1], Wr[1], Wl[2], Wr[2], pw2,
                       catB0, catB1, catB2,
                       bl[0], br[0], pb0, bl[1], br[1], bl[2], br[2], pb2,
                       cb0, cb1, cb2);

    // ---- Layer 0: swizzle x, one GEMM -> [xl|xr|res] fp16 rows of 768 ----
    swizzleA<<<dim3(4 * MT, 2), blk, 0, stream>>>(x, Asw, NN, 128);
    gemm_mfma<<<dim3(MT, 6), blk, 0, stream>>>(
        Asw, catB0, cb0, xlr, NN, 128, 768);
    // GAT + LN256 + resid(fp16 slice) + ELU -> h (fp32) + Asw (fp16, K=256)
    attn(0, 768, xlr + 512, nullptr, h, Asw, 0);

    // ---- Layer 1: one GEMM -> [xl|xr] rows of 512; resid = h ----
    gemm_mfma<<<dim3(MT, 4), blk, 0, stream>>>(
        Asw, catB1, cb1, xlr, NN, 256, 512);
    attn(1, 512, nullptr, h, nullptr, Asw, 1);   // writes Asw only

    // ---- Layer 2: single GEMM -> [xl|xr|res64] rows of 576 (9 groups) ----
    gemm_mfma<<<dim3(MT, 5), blk, 0, stream>>>(
        Asw, catB2, cb2, xlr, NN, 256, 576);
    attn(2, 576, xlr + 512, nullptr, (float*)d_out, nullptr, 2);
}